// Round 1
// baseline (279.821 us; speedup 1.0000x reference)
//
#include <hip/hip_runtime.h>

#define BATCH 8
#define CH 256
#define HWSZ 1024
#define BHW 8192

typedef _Float16 f16;
typedef _Float16 f16x8 __attribute__((ext_vector_type(8)));
typedef float f32x4 __attribute__((ext_vector_type(4)));

// ---------------- Kernel P: Q/K projections (fp32 vector), outputs f16 ----------------
// Q layout: [B, C, HW] flat  (== A matrix [8192 x 256] of the score GEMM)
// Kt layout: [B*HW, C]       (row j = pixel, col = channel)
__global__ __launch_bounds__(256) void proj_kernel(
    const float* __restrict__ x, const float* __restrict__ Wq, const float* __restrict__ bq,
    const float* __restrict__ Wk, const float* __restrict__ bk,
    f16* __restrict__ Qh, f16* __restrict__ Kth)
{
    const int b  = blockIdx.x >> 7;          // 8 batches
    const int s0 = (blockIdx.x & 127) * 8;   // 128 chunks of 8 pixels
    const int tid = threadIdx.x;

    __shared__ float xs[CH][8];
#pragma unroll
    for (int i = 0; i < 8; ++i) {
        int lin = i * 256 + tid;
        int c = lin >> 3, p = lin & 7;
        xs[c][p] = x[(b * CH + c) * HWSZ + s0 + p];
    }
    __syncthreads();

    const int co = tid;
    float accq[8], acck[8];
#pragma unroll
    for (int p = 0; p < 8; ++p) { accq[p] = 0.f; acck[p] = 0.f; }

    const float4* wqr = (const float4*)(Wq + co * CH);
    const float4* wkr = (const float4*)(Wk + co * CH);
    for (int c4 = 0; c4 < 64; ++c4) {
        float4 wq = wqr[c4];
        float4 wk = wkr[c4];
        float wqv[4] = {wq.x, wq.y, wq.z, wq.w};
        float wkv[4] = {wk.x, wk.y, wk.z, wk.w};
#pragma unroll
        for (int cc = 0; cc < 4; ++cc) {
            int c = c4 * 4 + cc;
#pragma unroll
            for (int p = 0; p < 8; ++p) {
                float xv = xs[c][p];
                accq[p] = fmaf(wqv[cc], xv, accq[p]);
                acck[p] = fmaf(wkv[cc], xv, acck[p]);
            }
        }
    }

    const float bqv = bq[co], bkv = bk[co];
    f16x8 qv;
#pragma unroll
    for (int p = 0; p < 8; ++p) qv[p] = (f16)(accq[p] + bqv);
    *(f16x8*)(Qh + (b * CH + co) * HWSZ + s0) = qv;
#pragma unroll
    for (int p = 0; p < 8; ++p)
        Kth[(b * HWSZ + s0 + p) * CH + co] = (f16)(acck[p] + bkv);
}

// ---------------- kmean: kmean[b][c] = (1/HW) * sum_s K[b,c,s] ----------------
__global__ __launch_bounds__(256) void kmean_kernel(const f16* __restrict__ Kth,
                                                    float* __restrict__ kmean)
{
    const int b = blockIdx.x;
    const int c = threadIdx.x;
    float s = 0.f;
    for (int j = 0; j < HWSZ; ++j) s += (float)Kth[(b * HWSZ + j) * CH + c];
    kmean[b * CH + c] = s * (1.0f / HWSZ);
}

// ---------------- Kernel S: score GEMM + row-max, f16 MFMA ----------------
// Block: 64 rows x 1024 cols (one batch block), grid (128, 8).
// 4 waves: wave (wr, wc) owns rows [wr*32, +32), cols chunk*128 + wc*64 .. +64.
__global__ __launch_bounds__(256) void score_kernel(
    const f16* __restrict__ Qh, const f16* __restrict__ Kth, float* __restrict__ rowmax)
{
    const int bidx = blockIdx.y;
    const int r0   = blockIdx.x * 64;
    const int tid  = threadIdx.x;
    const int wid  = tid >> 6, lane = tid & 63;
    const int wr = wid >> 1, wc = wid & 1;
    const int m = lane & 15, g = lane >> 4;

    // A fragments for this wave's 32 rows, K=256, resident in registers.
    const int rbase = r0 + wr * 32;
    f16x8 a[2][8];
#pragma unroll
    for (int t = 0; t < 2; ++t)
#pragma unroll
        for (int kk = 0; kk < 8; ++kk)
            a[t][kk] = *(const f16x8*)(Qh + (rbase + t * 16 + m) * CH + kk * 32 + 8 * g);

    float rm[2][4];
#pragma unroll
    for (int t = 0; t < 2; ++t)
#pragma unroll
        for (int jj = 0; jj < 4; ++jj) rm[t][jj] = -1e30f;

    const f32x4 vzero = {0.f, 0.f, 0.f, 0.f};

    for (int ch = 0; ch < 8; ++ch) {
        const int jb = bidx * HWSZ + ch * 128 + wc * 64;
        f32x4 acc[2][4];
#pragma unroll
        for (int t = 0; t < 2; ++t)
#pragma unroll
            for (int u = 0; u < 4; ++u) acc[t][u] = vzero;

#pragma unroll
        for (int kk = 0; kk < 8; ++kk) {
            f16x8 bf[4];
#pragma unroll
            for (int u = 0; u < 4; ++u)
                bf[u] = *(const f16x8*)(Kth + (jb + u * 16 + m) * CH + kk * 32 + 8 * g);
#pragma unroll
            for (int t = 0; t < 2; ++t)
#pragma unroll
                for (int u = 0; u < 4; ++u)
                    acc[t][u] = __builtin_amdgcn_mfma_f32_16x16x32_f16(a[t][kk], bf[u], acc[t][u], 0, 0, 0);
        }

#pragma unroll
        for (int t = 0; t < 2; ++t)
#pragma unroll
            for (int jj = 0; jj < 4; ++jj) {
                float v = acc[t][0][jj];
                v = fmaxf(v, acc[t][1][jj]);
                v = fmaxf(v, acc[t][2][jj]);
                v = fmaxf(v, acc[t][3][jj]);
                rm[t][jj] = fmaxf(rm[t][jj], v);
            }
    }

    // Reduce max over the 16 column lanes (D col = lane&15).
#pragma unroll
    for (int d = 1; d < 16; d <<= 1)
#pragma unroll
        for (int t = 0; t < 2; ++t)
#pragma unroll
            for (int jj = 0; jj < 4; ++jj)
                rm[t][jj] = fmaxf(rm[t][jj], __shfl_xor(rm[t][jj], d, 64));

    __shared__ float lds_rm[64][2];
    if (m == 0) {
#pragma unroll
        for (int t = 0; t < 2; ++t)
#pragma unroll
            for (int jj = 0; jj < 4; ++jj)
                lds_rm[wr * 32 + t * 16 + 4 * g + jj][wc] = rm[t][jj];
    }
    __syncthreads();
    if (tid < 64)
        rowmax[(r0 + tid) * BATCH + bidx] = fmaxf(lds_rm[tid][0], lds_rm[tid][1]);
}

// ---------------- R1: logits[r] = (sum_b rowmax[r,b] + q_r . kmean_b) / 128 ----------------
__global__ __launch_bounds__(256) void logits_kernel(
    const f16* __restrict__ Qh, const float* __restrict__ kmean,
    const float* __restrict__ rowmax, float* __restrict__ logits)
{
    __shared__ float km[BATCH][CH];
    const int tid = threadIdx.x;
#pragma unroll
    for (int i = 0; i < 8; ++i) km[i][tid] = kmean[i * 256 + tid];
    __syncthreads();

    const int r = blockIdx.x * 256 + tid;
    float acc[8];
#pragma unroll
    for (int b = 0; b < 8; ++b) acc[b] = 0.f;

    const f16x8* q = (const f16x8*)(Qh + (long)r * CH);
    for (int c8 = 0; c8 < 32; ++c8) {
        f16x8 qv = q[c8];
#pragma unroll
        for (int i = 0; i < 8; ++i) {
            float qf = (float)qv[i];
#pragma unroll
            for (int b = 0; b < 8; ++b)
                acc[b] = fmaf(qf, km[b][c8 * 8 + i], acc[b]);
        }
    }
    float lg = 0.f;
#pragma unroll
    for (int b = 0; b < 8; ++b) lg += rowmax[r * 8 + b] + acc[b];
    logits[r] = lg * (1.0f / 128.0f);
}

// ---------------- R2: softmax over HW per batch ----------------
__global__ __launch_bounds__(256) void softmax_kernel(const float* __restrict__ logits,
                                                      float* __restrict__ wgt)
{
    const int br = blockIdx.x, tid = threadIdx.x;
    __shared__ float red[256];
    float l[4];
#pragma unroll
    for (int i = 0; i < 4; ++i) l[i] = logits[br * HWSZ + i * 256 + tid];

    float mx = fmaxf(fmaxf(l[0], l[1]), fmaxf(l[2], l[3]));
    red[tid] = mx;
    __syncthreads();
    for (int s = 128; s > 0; s >>= 1) {
        if (tid < s) red[tid] = fmaxf(red[tid], red[tid + s]);
        __syncthreads();
    }
    mx = red[0];
    __syncthreads();

    float e[4], sm = 0.f;
#pragma unroll
    for (int i = 0; i < 4; ++i) { e[i] = expf(l[i] - mx); sm += e[i]; }
    red[tid] = sm;
    __syncthreads();
    for (int s = 128; s > 0; s >>= 1) {
        if (tid < s) red[tid] += red[tid + s];
        __syncthreads();
    }
    const float inv = 1.0f / red[0];
#pragma unroll
    for (int i = 0; i < 4; ++i)
        wgt[br * HWSZ + i * 256 + tid] = e[i] * inv;
}

// ---------------- Kernel O: out = Wo @ (x * wgt) + bo ----------------
__global__ __launch_bounds__(256) void outconv_kernel(
    const float* __restrict__ x, const float* __restrict__ Wo, const float* __restrict__ bo,
    const float* __restrict__ wgt, float* __restrict__ out)
{
    const int b  = blockIdx.x >> 7;
    const int s0 = (blockIdx.x & 127) * 8;
    const int tid = threadIdx.x;

    __shared__ float xs[CH][8];
    __shared__ float ws[8];
#pragma unroll
    for (int i = 0; i < 8; ++i) {
        int lin = i * 256 + tid;
        int c = lin >> 3, p = lin & 7;
        xs[c][p] = x[(b * CH + c) * HWSZ + s0 + p];
    }
    if (tid < 8) ws[tid] = wgt[b * HWSZ + s0 + tid];
    __syncthreads();

    const int co = tid;
    float acc[8];
#pragma unroll
    for (int p = 0; p < 8; ++p) acc[p] = 0.f;

    const float4* wor = (const float4*)(Wo + co * CH);
    for (int c4 = 0; c4 < 64; ++c4) {
        float4 wo = wor[c4];
        float wov[4] = {wo.x, wo.y, wo.z, wo.w};
#pragma unroll
        for (int cc = 0; cc < 4; ++cc) {
            int c = c4 * 4 + cc;
#pragma unroll
            for (int p = 0; p < 8; ++p)
                acc[p] = fmaf(wov[cc], xs[c][p], acc[p]);
        }
    }

    const float bov = bo[co];
    float o[8];
#pragma unroll
    for (int p = 0; p < 8; ++p) o[p] = fmaf(acc[p], ws[p], bov);
    float4 v0 = {o[0], o[1], o[2], o[3]};
    float4 v1 = {o[4], o[5], o[6], o[7]};
    float4* dst = (float4*)(out + (b * CH + co) * HWSZ + s0);
    dst[0] = v0;
    dst[1] = v1;
}

extern "C" void kernel_launch(void* const* d_in, const int* in_sizes, int n_in,
                              void* d_out, int out_size, void* d_ws, size_t ws_size,
                              hipStream_t stream)
{
    const float* x  = (const float*)d_in[0];
    const float* Wq = (const float*)d_in[1];
    const float* bq = (const float*)d_in[2];
    const float* Wk = (const float*)d_in[3];
    const float* bk = (const float*)d_in[4];
    const float* Wo = (const float*)d_in[5];
    const float* bo = (const float*)d_in[6];
    float* out = (float*)d_out;

    char* ws = (char*)d_ws;
    f16*   Qh     = (f16*)(ws);                                 // 4 MB
    f16*   Kth    = (f16*)(ws + (4 << 20));                     // 4 MB
    float* rowmax = (float*)(ws + (8 << 20));                   // 256 KB
    float* kmean  = (float*)(ws + (8 << 20) + (256 << 10));     // 8 KB
    float* logits = (float*)(ws + (8 << 20) + (264 << 10));     // 32 KB
    float* wgt    = (float*)(ws + (8 << 20) + (296 << 10));     // 32 KB

    proj_kernel   <<<dim3(1024),    256, 0, stream>>>(x, Wq, bq, Wk, bk, Qh, Kth);
    kmean_kernel  <<<dim3(8),       256, 0, stream>>>(Kth, kmean);
    score_kernel  <<<dim3(128, 8),  256, 0, stream>>>(Qh, Kth, rowmax);
    logits_kernel <<<dim3(32),      256, 0, stream>>>(Qh, kmean, rowmax, logits);
    softmax_kernel<<<dim3(8),       256, 0, stream>>>(logits, wgt);
    outconv_kernel<<<dim3(1024),    256, 0, stream>>>(x, Wo, bo, wgt, out);
}

// Round 2
// 151.818 us; speedup vs baseline: 1.8431x; 1.8431x over previous
//
#include <hip/hip_runtime.h>

#define BATCH 8
#define CH 256
#define HWSZ 1024
#define BHW 8192

typedef _Float16 f16;
typedef _Float16 f16x8 __attribute__((ext_vector_type(8)));
typedef float f32x4 __attribute__((ext_vector_type(4)));
typedef __attribute__((address_space(3))) unsigned int lds_u32;
typedef __attribute__((address_space(1))) const unsigned int glob_u32;

// ---------------- xmean: xmean[b*256+c] = mean over HW of x[b,c,:] ----------------
__global__ __launch_bounds__(256) void xmean_kernel(const float* __restrict__ x,
                                                    float* __restrict__ xmean)
{
    const int row  = blockIdx.x * 64 + (threadIdx.x >> 2);   // [0, 2048)
    const int part = threadIdx.x & 3;
    const float4* p = (const float4*)(x + (size_t)row * HWSZ + part * 256);
    float s = 0.f;
#pragma unroll 8
    for (int i = 0; i < 64; ++i) { float4 v = p[i]; s += v.x + v.y + v.z + v.w; }
    s += __shfl_xor(s, 1, 64);
    s += __shfl_xor(s, 2, 64);
    if (part == 0) xmean[row] = s * (1.0f / HWSZ);
}

// ---------------- kmean[b][co] = Wk[co,:] . xmean[b,:] + bk[co]  (exact, linear) ----------------
__global__ __launch_bounds__(256) void kmeanW_kernel(
    const float* __restrict__ Wk, const float* __restrict__ bk,
    const float* __restrict__ xmean, float* __restrict__ kmean)
{
    __shared__ float xm[BATCH * CH];
    const int tid = threadIdx.x;
#pragma unroll
    for (int i = 0; i < 8; ++i) xm[i * 256 + tid] = xmean[i * 256 + tid];
    __syncthreads();

    float acc[8];
#pragma unroll
    for (int b = 0; b < 8; ++b) acc[b] = 0.f;
    const float4* w = (const float4*)(Wk + tid * CH);
    for (int c4 = 0; c4 < 64; ++c4) {
        float4 wv = w[c4];
        float wa[4] = {wv.x, wv.y, wv.z, wv.w};
#pragma unroll
        for (int cc = 0; cc < 4; ++cc)
#pragma unroll
            for (int b = 0; b < 8; ++b)
                acc[b] = fmaf(wa[cc], xm[b * 256 + c4 * 4 + cc], acc[b]);
    }
    const float bkv = bk[tid];
#pragma unroll
    for (int b = 0; b < 8; ++b) kmean[b * 256 + tid] = acc[b] + bkv;
}

// ---------------- Kernel P: Q/K projections (fp32), 32 pixels/block ----------------
// Qh: [B,C,HW] f16 flat.  Ksw: swizzled [j][byte ^ ((j&7)<<4)] f16 rows of 512B.
__global__ __launch_bounds__(256) void proj_kernel(
    const float* __restrict__ x, const float* __restrict__ Wq, const float* __restrict__ bq,
    const float* __restrict__ Wk, const float* __restrict__ bk,
    f16* __restrict__ Qh, char* __restrict__ Ksw)
{
    const int b  = blockIdx.x >> 5;
    const int s0 = (blockIdx.x & 31) * 32;
    const int tid = threadIdx.x;

    __shared__ float xs[CH][32];
#pragma unroll
    for (int i = 0; i < 32; ++i) {
        int c = i * 8 + (tid >> 5), p = tid & 31;
        xs[c][p] = x[((size_t)b * CH + c) * HWSZ + s0 + p];
    }
    __syncthreads();

    float accq[32], acck[32];
#pragma unroll
    for (int p = 0; p < 32; ++p) { accq[p] = 0.f; acck[p] = 0.f; }

    const float4* wqr = (const float4*)(Wq + tid * CH);
    const float4* wkr = (const float4*)(Wk + tid * CH);
    for (int c4 = 0; c4 < 64; ++c4) {
        float4 wq = wqr[c4];
        float4 wk = wkr[c4];
        float wqa[4] = {wq.x, wq.y, wq.z, wq.w};
        float wka[4] = {wk.x, wk.y, wk.z, wk.w};
#pragma unroll
        for (int cc = 0; cc < 4; ++cc) {
            const int c = c4 * 4 + cc;
#pragma unroll
            for (int p4 = 0; p4 < 8; ++p4) {
                float4 xv = *(const float4*)&xs[c][p4 * 4];
                float xa[4] = {xv.x, xv.y, xv.z, xv.w};
#pragma unroll
                for (int l = 0; l < 4; ++l) {
                    accq[p4 * 4 + l] = fmaf(wqa[cc], xa[l], accq[p4 * 4 + l]);
                    acck[p4 * 4 + l] = fmaf(wka[cc], xa[l], acck[p4 * 4 + l]);
                }
            }
        }
    }

    const float bqv = bq[tid], bkv = bk[tid];
#pragma unroll
    for (int p8 = 0; p8 < 4; ++p8) {
        f16x8 qv;
#pragma unroll
        for (int l = 0; l < 8; ++l) qv[l] = (f16)(accq[p8 * 8 + l] + bqv);
        *(f16x8*)(Qh + ((size_t)b * CH + tid) * HWSZ + s0 + p8 * 8) = qv;
    }
#pragma unroll
    for (int p = 0; p < 32; ++p) {
        const int j = b * HWSZ + s0 + p;
        const int byte = (tid * 2) ^ ((j & 7) << 4);
        *(f16*)(Ksw + (size_t)j * 512 + byte) = (f16)(acck[p] + bkv);
    }
}

// ---------------- Kernel S: score GEMM + row-max ----------------
// grid 256 (1-D): batch = bid&7 (XCD-affine), rowblock = bid>>3 (256 rows).
// 8 waves: wr=wid>>1 picks 64 rows, wc=wid&1 picks 32 of 64 staged cols.
__global__ __launch_bounds__(512, 2) void score_kernel(
    const f16* __restrict__ Qh, const char* __restrict__ Ksw, float* __restrict__ rowmax)
{
    __shared__ __align__(16) char kbuf[2][32768];   // 64 cols x 512B, double buffered
    __shared__ float lds_rm[256][2];

    const int batch = blockIdx.x & 7;
    const int r0    = (blockIdx.x >> 3) * 256;
    const int tid   = threadIdx.x;
    const int lane  = tid & 63;
    const int wid   = tid >> 6;
    const int wr = wid >> 1, wc = wid & 1;
    const int m = lane & 15, g = lane >> 4;
    const int rbase = r0 + wr * 64;

    const char* kbase = Ksw + (size_t)batch * HWSZ * 512;

#define STAGE(buf, ch)                                                                  \
    {                                                                                   \
        const char* _src = kbase + (ch) * 64 * 512 + tid * 16;                          \
        char* _dst = &kbuf[buf][tid * 16];                                              \
        __builtin_amdgcn_global_load_lds((glob_u32*)(_src),        (lds_u32*)(_dst),        16, 0, 0); \
        __builtin_amdgcn_global_load_lds((glob_u32*)(_src + 8192), (lds_u32*)(_dst + 8192), 16, 0, 0); \
        __builtin_amdgcn_global_load_lds((glob_u32*)(_src + 16384),(lds_u32*)(_dst + 16384),16, 0, 0); \
        __builtin_amdgcn_global_load_lds((glob_u32*)(_src + 24576),(lds_u32*)(_dst + 24576),16, 0, 0); \
    }

    STAGE(0, 0);

    // A fragments: 64 rows x K=256 in registers.
    f16x8 a[4][8];
#pragma unroll
    for (int t = 0; t < 4; ++t)
#pragma unroll
        for (int kk = 0; kk < 8; ++kk)
            a[t][kk] = *(const f16x8*)(Qh + (size_t)(rbase + t * 16 + m) * CH + kk * 32 + 8 * g);

    // Precomputed swizzled B offsets (chunk-invariant).
    int boff[8][2];
    {
        const int sw = (m & 7) << 4;
#pragma unroll
        for (int kk = 0; kk < 8; ++kk)
#pragma unroll
            for (int u2 = 0; u2 < 2; ++u2) {
                const int col = wc * 32 + u2 * 16 + m;
                boff[kk][u2] = col * 512 + ((kk * 64 + g * 16) ^ sw);
            }
    }

    float rm[4][4];
#pragma unroll
    for (int t = 0; t < 4; ++t)
#pragma unroll
        for (int jj = 0; jj < 4; ++jj) rm[t][jj] = -1e30f;

    __syncthreads();   // drains vmcnt: chunk 0 staged

    int cur = 0;
    for (int ch = 0; ch < 16; ++ch) {
        if (ch < 15) STAGE(cur ^ 1, ch + 1);

        const char* kb = &kbuf[cur][0];
        f32x4 acc[4][2];
        const f32x4 vz = {0.f, 0.f, 0.f, 0.f};
#pragma unroll
        for (int t = 0; t < 4; ++t) { acc[t][0] = vz; acc[t][1] = vz; }

#pragma unroll
        for (int kk = 0; kk < 8; ++kk) {
            f16x8 bfr[2];
            bfr[0] = *(const f16x8*)(kb + boff[kk][0]);
            bfr[1] = *(const f16x8*)(kb + boff[kk][1]);
#pragma unroll
            for (int t = 0; t < 4; ++t) {
                acc[t][0] = __builtin_amdgcn_mfma_f32_16x16x32_f16(a[t][kk], bfr[0], acc[t][0], 0, 0, 0);
                acc[t][1] = __builtin_amdgcn_mfma_f32_16x16x32_f16(a[t][kk], bfr[1], acc[t][1], 0, 0, 0);
            }
        }

#pragma unroll
        for (int t = 0; t < 4; ++t)
#pragma unroll
            for (int jj = 0; jj < 4; ++jj)
                rm[t][jj] = fmaxf(rm[t][jj], fmaxf(acc[t][0][jj], acc[t][1][jj]));

        __syncthreads();   // staged chunk complete (vmcnt drain) + buffer handoff
        cur ^= 1;
    }
#undef STAGE

    // Reduce over the 16 column lanes.
#pragma unroll
    for (int d = 1; d < 16; d <<= 1)
#pragma unroll
        for (int t = 0; t < 4; ++t)
#pragma unroll
            for (int jj = 0; jj < 4; ++jj)
                rm[t][jj] = fmaxf(rm[t][jj], __shfl_xor(rm[t][jj], d, 64));

    if (m == 0) {
#pragma unroll
        for (int t = 0; t < 4; ++t)
#pragma unroll
            for (int jj = 0; jj < 4; ++jj)
                lds_rm[wr * 64 + t * 16 + g * 4 + jj][wc] = rm[t][jj];
    }
    __syncthreads();
    if (tid < 256)
        rowmax[(size_t)(r0 + tid) * BATCH + batch] = fmaxf(lds_rm[tid][0], lds_rm[tid][1]);
}

// ---------------- R1: logits[r] = (sum_b rowmax[r,b] + q_r . kmean_b) / 128 ----------------
__global__ __launch_bounds__(256) void logits_kernel(
    const f16* __restrict__ Qh, const float* __restrict__ kmean,
    const float* __restrict__ rowmax, float* __restrict__ logits)
{
    __shared__ float km[BATCH][CH];
    const int tid = threadIdx.x;
#pragma unroll
    for (int i = 0; i < 8; ++i) km[i][tid] = kmean[i * 256 + tid];
    __syncthreads();

    const int r = blockIdx.x * 256 + tid;
    float acc[8];
#pragma unroll
    for (int b = 0; b < 8; ++b) acc[b] = 0.f;

    const f16x8* q = (const f16x8*)(Qh + (size_t)r * CH);
    for (int c8 = 0; c8 < 32; ++c8) {
        f16x8 qv = q[c8];
        float qf[8];
#pragma unroll
        for (int i = 0; i < 8; ++i) qf[i] = (float)qv[i];
#pragma unroll
        for (int b = 0; b < 8; ++b) {
            float4 k0 = *(const float4*)&km[b][c8 * 8];
            float4 k1 = *(const float4*)&km[b][c8 * 8 + 4];
            acc[b] = fmaf(qf[0], k0.x, acc[b]); acc[b] = fmaf(qf[1], k0.y, acc[b]);
            acc[b] = fmaf(qf[2], k0.z, acc[b]); acc[b] = fmaf(qf[3], k0.w, acc[b]);
            acc[b] = fmaf(qf[4], k1.x, acc[b]); acc[b] = fmaf(qf[5], k1.y, acc[b]);
            acc[b] = fmaf(qf[6], k1.z, acc[b]); acc[b] = fmaf(qf[7], k1.w, acc[b]);
        }
    }
    float lg = 0.f;
#pragma unroll
    for (int b = 0; b < 8; ++b) lg += rowmax[(size_t)r * 8 + b] + acc[b];
    logits[r] = lg * (1.0f / 128.0f);
}

// ---------------- R2: softmax over HW per batch ----------------
__global__ __launch_bounds__(256) void softmax_kernel(const float* __restrict__ logits,
                                                      float* __restrict__ wgt)
{
    const int br = blockIdx.x, tid = threadIdx.x;
    __shared__ float red[256];
    float l[4];
#pragma unroll
    for (int i = 0; i < 4; ++i) l[i] = logits[br * HWSZ + i * 256 + tid];

    float mx = fmaxf(fmaxf(l[0], l[1]), fmaxf(l[2], l[3]));
    red[tid] = mx;
    __syncthreads();
    for (int s = 128; s > 0; s >>= 1) {
        if (tid < s) red[tid] = fmaxf(red[tid], red[tid + s]);
        __syncthreads();
    }
    mx = red[0];
    __syncthreads();

    float e[4], sm = 0.f;
#pragma unroll
    for (int i = 0; i < 4; ++i) { e[i] = expf(l[i] - mx); sm += e[i]; }
    red[tid] = sm;
    __syncthreads();
    for (int s = 128; s > 0; s >>= 1) {
        if (tid < s) red[tid] += red[tid + s];
        __syncthreads();
    }
    const float inv = 1.0f / red[0];
#pragma unroll
    for (int i = 0; i < 4; ++i)
        wgt[br * HWSZ + i * 256 + tid] = e[i] * inv;
}

// ---------------- Kernel O: out = Wo @ (x * wgt) + bo, 32 pixels/block ----------------
__global__ __launch_bounds__(256) void outconv_kernel(
    const float* __restrict__ x, const float* __restrict__ Wo, const float* __restrict__ bo,
    const float* __restrict__ wgt, float* __restrict__ out)
{
    const int b  = blockIdx.x >> 5;
    const int s0 = (blockIdx.x & 31) * 32;
    const int tid = threadIdx.x;

    __shared__ float xs[CH][32];
    __shared__ float ws[32];
#pragma unroll
    for (int i = 0; i < 32; ++i) {
        int c = i * 8 + (tid >> 5), p = tid & 31;
        xs[c][p] = x[((size_t)b * CH + c) * HWSZ + s0 + p];
    }
    if (tid < 32) ws[tid] = wgt[b * HWSZ + s0 + tid];
    __syncthreads();

    float acc[32];
#pragma unroll
    for (int p = 0; p < 32; ++p) acc[p] = 0.f;

    const float4* wor = (const float4*)(Wo + tid * CH);
    for (int c4 = 0; c4 < 64; ++c4) {
        float4 wo = wor[c4];
        float wa[4] = {wo.x, wo.y, wo.z, wo.w};
#pragma unroll
        for (int cc = 0; cc < 4; ++cc) {
            const int c = c4 * 4 + cc;
#pragma unroll
            for (int p4 = 0; p4 < 8; ++p4) {
                float4 xv = *(const float4*)&xs[c][p4 * 4];
                acc[p4 * 4 + 0] = fmaf(wa[cc], xv.x, acc[p4 * 4 + 0]);
                acc[p4 * 4 + 1] = fmaf(wa[cc], xv.y, acc[p4 * 4 + 1]);
                acc[p4 * 4 + 2] = fmaf(wa[cc], xv.z, acc[p4 * 4 + 2]);
                acc[p4 * 4 + 3] = fmaf(wa[cc], xv.w, acc[p4 * 4 + 3]);
            }
        }
    }

    const float bov = bo[tid];
#pragma unroll
    for (int p4 = 0; p4 < 8; ++p4) {
        float4 v;
        v.x = fmaf(acc[p4 * 4 + 0], ws[p4 * 4 + 0], bov);
        v.y = fmaf(acc[p4 * 4 + 1], ws[p4 * 4 + 1], bov);
        v.z = fmaf(acc[p4 * 4 + 2], ws[p4 * 4 + 2], bov);
        v.w = fmaf(acc[p4 * 4 + 3], ws[p4 * 4 + 3], bov);
        *(float4*)(out + ((size_t)b * CH + tid) * HWSZ + s0 + p4 * 4) = v;
    }
}

extern "C" void kernel_launch(void* const* d_in, const int* in_sizes, int n_in,
                              void* d_out, int out_size, void* d_ws, size_t ws_size,
                              hipStream_t stream)
{
    const float* x  = (const float*)d_in[0];
    const float* Wq = (const float*)d_in[1];
    const float* bq = (const float*)d_in[2];
    const float* Wk = (const float*)d_in[3];
    const float* bk = (const float*)d_in[4];
    const float* Wo = (const float*)d_in[5];
    const float* bo = (const float*)d_in[6];
    float* out = (float*)d_out;

    char* ws = (char*)d_ws;
    f16*   Qh     = (f16*)(ws);                                  // 4 MB
    char*  Ksw    = (char*)(ws + (4 << 20));                     // 4 MB (swizzled f16)
    float* rowmax = (float*)(ws + (8 << 20));                    // 256 KB
    float* kmean  = (float*)(ws + (8 << 20) + (256 << 10));      // 8 KB
    float* xmean  = (float*)(ws + (8 << 20) + (264 << 10));      // 8 KB
    float* logits = (float*)(ws + (8 << 20) + (272 << 10));      // 32 KB
    float* wgt    = (float*)(ws + (8 << 20) + (304 << 10));      // 32 KB

    xmean_kernel  <<<dim3(32),  256, 0, stream>>>(x, xmean);
    kmeanW_kernel <<<dim3(1),   256, 0, stream>>>(Wk, bk, xmean, kmean);
    proj_kernel   <<<dim3(256), 256, 0, stream>>>(x, Wq, bq, Wk, bk, Qh, Ksw);
    score_kernel  <<<dim3(256), 512, 0, stream>>>(Qh, Ksw, rowmax);
    logits_kernel <<<dim3(32),  256, 0, stream>>>(Qh, kmean, rowmax, logits);
    softmax_kernel<<<dim3(8),   256, 0, stream>>>(logits, wgt);
    outconv_kernel<<<dim3(256), 256, 0, stream>>>(x, Wo, bo, wgt, out);
}

// Round 3
// 108.191 us; speedup vs baseline: 2.5864x; 1.4032x over previous
//
#include <hip/hip_runtime.h>

#define BATCH 8
#define CH 256
#define HWSZ 1024
#define BHW 8192

typedef _Float16 f16;
typedef _Float16 f16x4 __attribute__((ext_vector_type(4)));
typedef _Float16 f16x8 __attribute__((ext_vector_type(8)));
typedef float f32x4 __attribute__((ext_vector_type(4)));
typedef unsigned long long u64;
typedef __attribute__((address_space(3))) unsigned int lds_u32;
typedef __attribute__((address_space(1))) const unsigned int glob_u32;

// ---------------- xmean: xmean[b*256+c] = mean over HW of x[b,c,:] ----------------
__global__ __launch_bounds__(256) void xmean_kernel(const float* __restrict__ x,
                                                    float* __restrict__ xmean)
{
    const int row  = blockIdx.x * 64 + (threadIdx.x >> 2);   // [0, 2048)
    const int part = threadIdx.x & 3;
    const float4* p = (const float4*)(x + (size_t)row * HWSZ + part * 256);
    float s = 0.f;
#pragma unroll 8
    for (int i = 0; i < 64; ++i) { float4 v = p[i]; s += v.x + v.y + v.z + v.w; }
    s += __shfl_xor(s, 1, 64);
    s += __shfl_xor(s, 2, 64);
    if (part == 0) xmean[row] = s * (1.0f / HWSZ);
}

// ---------------- kmean[b][co] = Wk[co,:] . xmean[b,:] + bk[co]  (exact fp32) ----------------
__global__ __launch_bounds__(256) void kmeanW_kernel(
    const float* __restrict__ Wk, const float* __restrict__ bk,
    const float* __restrict__ xmean, float* __restrict__ kmean)
{
    __shared__ float xm[BATCH * CH];
    const int tid = threadIdx.x;
#pragma unroll
    for (int i = 0; i < 8; ++i) xm[i * 256 + tid] = xmean[i * 256 + tid];
    __syncthreads();

    float acc[8];
#pragma unroll
    for (int b = 0; b < 8; ++b) acc[b] = 0.f;
    const float4* w = (const float4*)(Wk + tid * CH);
    for (int c4 = 0; c4 < 64; ++c4) {
        float4 wv = w[c4];
        float wa[4] = {wv.x, wv.y, wv.z, wv.w};
#pragma unroll
        for (int cc = 0; cc < 4; ++cc)
#pragma unroll
            for (int b = 0; b < 8; ++b)
                acc[b] = fmaf(wa[cc], xm[b * 256 + c4 * 4 + cc], acc[b]);
    }
    const float bkv = bk[tid];
#pragma unroll
    for (int b = 0; b < 8; ++b) kmean[b * 256 + tid] = acc[b] + bkv;
}

// ---------------- pgemm: Q/K/Y projections via f16 MFMA with split-x (K=512) ----------------
// grid (128.. actually 256 px-tiles of 32, 3 mblocks). mb: 0=Q, 1=K, 2=Y(->d_out fp32).
// B-operand tile: kbuf[px][1024B] = [hi f16 x 256 | lo f16 x 256], 16B-XOR swizzle key px&7.
__global__ __launch_bounds__(256, 2) void pgemm_kernel(
    const float* __restrict__ x,
    const float* __restrict__ Wq, const float* __restrict__ Wk, const float* __restrict__ Wo,
    const float* __restrict__ bq, const float* __restrict__ bk,
    f16* __restrict__ Qh, char* __restrict__ Ksw, float* __restrict__ Yout)
{
    __shared__ __align__(16) char kbuf[32 * 1024];     // 32 KB: x^T split tile
    __shared__ __align__(16) float xt[256][36];        // 36 KB: fp32 transpose staging (reused as bounce)
    f16* tile = (f16*)&xt[0][0];                       // bounce alias (16 KB needed)
    char* tileb = (char*)&xt[0][0];

    const int mb   = blockIdx.y;
    const int pxg0 = blockIdx.x * 32;
    const int b    = pxg0 >> 10;
    const int hw0  = pxg0 & 1023;
    const int tid  = threadIdx.x;
    const int lane = tid & 63;
    const int wid  = tid >> 6;          // 4 waves; wave owns 64 co rows
    const int m = lane & 15, g = lane >> 4;

    // ---- Phase A: coalesced load of x[b][0..255][hw0..hw0+32) into xt (fp32) ----
    {
        const int f4 = tid & 7;         // 8 float4 = 32 px
        const int cs = tid >> 3;        // 32 c per pass
#pragma unroll
        for (int pass = 0; pass < 8; ++pass) {
            const int c = pass * 32 + cs;
            float4 v = *(const float4*)(x + ((size_t)b * CH + c) * HWSZ + hw0 + f4 * 4);
            *(float4*)&xt[c][f4 * 4] = v;
        }
    }
    __syncthreads();

    // ---- Phase B: transpose + hi/lo split into kbuf ----
    {
        const int px = tid & 31;
        const int q8 = tid >> 5;        // 8 c-parts of 32
        const int sw = (px & 7) << 4;
#pragma unroll
        for (int r = 0; r < 4; ++r) {
            f16x8 hi, lo;
#pragma unroll
            for (int i = 0; i < 8; ++i) {
                const int c = q8 * 32 + r * 8 + i;
                float v = xt[c][px];
                f16 h = (f16)v;
                hi[i] = h;
                lo[i] = (f16)(v - (float)h);
            }
            const int base = q8 * 64 + r * 16;
            *(f16x8*)(kbuf + px * 1024 + (base ^ sw)) = hi;
            *(f16x8*)(kbuf + px * 1024 + 512 + (base ^ sw)) = lo;
        }
    }

    // ---- A-frags: W rows f32 -> f16 in registers (same for both k-halves) ----
    const float* Wsel = (mb == 0) ? Wq : (mb == 1) ? Wk : Wo;
    f16x8 a[4][8];
#pragma unroll
    for (int t = 0; t < 4; ++t)
#pragma unroll
        for (int kk = 0; kk < 8; ++kk) {
            const float* wrow = Wsel + (size_t)(wid * 64 + t * 16 + m) * CH + kk * 32 + g * 8;
            float4 w0 = *(const float4*)(wrow);
            float4 w1 = *(const float4*)(wrow + 4);
            f16x8 av;
            av[0] = (f16)w0.x; av[1] = (f16)w0.y; av[2] = (f16)w0.z; av[3] = (f16)w0.w;
            av[4] = (f16)w1.x; av[5] = (f16)w1.y; av[6] = (f16)w1.z; av[7] = (f16)w1.w;
            a[t][kk] = av;
        }

    __syncthreads();   // kbuf ready

    // ---- MFMA main loop: K = 512 (hi 256 + lo 256) ----
    f32x4 acc[4][2];
    const f32x4 vz = {0.f, 0.f, 0.f, 0.f};
#pragma unroll
    for (int t = 0; t < 4; ++t) { acc[t][0] = vz; acc[t][1] = vz; }

    const int sw0 = (m & 7) << 4;   // px&7 == m&7 for both u (16+m keeps low 3 bits)
#pragma unroll
    for (int ks = 0; ks < 16; ++ks) {
        const int X = ks * 64 + g * 16;
        f16x8 b0 = *(const f16x8*)(kbuf + m * 1024 + (X ^ sw0));
        f16x8 b1 = *(const f16x8*)(kbuf + (16 + m) * 1024 + (X ^ sw0));
#pragma unroll
        for (int t = 0; t < 4; ++t) {
            acc[t][0] = __builtin_amdgcn_mfma_f32_16x16x32_f16(a[t][ks & 7], b0, acc[t][0], 0, 0, 0);
            acc[t][1] = __builtin_amdgcn_mfma_f32_16x16x32_f16(a[t][ks & 7], b1, acc[t][1], 0, 0, 0);
        }
    }

    // ---- Epilogue ----
    if (mb == 2) {
        // Y: direct fp32 stores into d_out (gate applied later, in-place).
#pragma unroll
        for (int t = 0; t < 4; ++t)
#pragma unroll
            for (int u = 0; u < 2; ++u)
#pragma unroll
                for (int j = 0; j < 4; ++j) {
                    const int co = wid * 64 + t * 16 + 4 * g + j;
                    Yout[((size_t)b * CH + co) * HWSZ + hw0 + u * 16 + m] = acc[t][u][j];
                }
        return;
    }

    const float* bias = (mb == 0) ? bq : bk;
    if (mb == 0) {
        // Q bounce: tile[co][px ^ ((co&3)<<3)], co&3 == j.
#pragma unroll
        for (int t = 0; t < 4; ++t) {
            const int co0 = wid * 64 + t * 16 + 4 * g;
            float4 bv = *(const float4*)(bias + co0);
            float ba[4] = {bv.x, bv.y, bv.z, bv.w};
#pragma unroll
            for (int u = 0; u < 2; ++u) {
                const int px = u * 16 + m;
#pragma unroll
                for (int j = 0; j < 4; ++j)
                    tile[(co0 + j) * 32 + (px ^ (j << 3))] = (f16)(acc[t][u][j] + ba[j]);
            }
        }
        __syncthreads();
        // read + coalesced global store: Qh[b][co][hw0 + run*8 .. +8]
#pragma unroll
        for (int pass = 0; pass < 4; ++pass) {
            const int co  = pass * 64 + (tid >> 2);
            const int run = tid & 3;
            f16x8 v = *(const f16x8*)(tile + co * 32 + ((run * 8) ^ ((co & 3) << 3)));
            *(f16x8*)(Qh + ((size_t)b * CH + co) * HWSZ + hw0 + run * 8) = v;
        }
    } else {
        // K bounce: tileK[px][ (2co) ^ ((px&15)<<3) ], b64-packed j-quads.
#pragma unroll
        for (int t = 0; t < 4; ++t) {
            const int co0 = wid * 64 + t * 16 + 4 * g;
            float4 bv = *(const float4*)(bias + co0);
            float ba[4] = {bv.x, bv.y, bv.z, bv.w};
#pragma unroll
            for (int u = 0; u < 2; ++u) {
                const int px = u * 16 + m;
                f16x4 pk;
#pragma unroll
                for (int j = 0; j < 4; ++j) pk[j] = (f16)(acc[t][u][j] + ba[j]);
                *(f16x4*)(tileb + px * 512 + ((co0 * 2) ^ (m << 3))) = pk;
            }
        }
        __syncthreads();
        // read + global store to swizzled Ksw rows.
        const int px = tid & 31;
        const int rp = tid >> 5;
        const int kloc = (px & 15) << 3;
        const int kglb = (px & 7) << 4;
        char* grow = Ksw + (size_t)(pxg0 + px) * 512;
#pragma unroll
        for (int i = 0; i < 4; ++i) {
            const int r = rp + i * 8;
            u64 a0 = *(const u64*)(tileb + px * 512 + ((r * 16) ^ kloc));
            u64 a1 = *(const u64*)(tileb + px * 512 + ((r * 16 + 8) ^ kloc));
            char* gdst = grow + ((r * 16) ^ kglb);
            *(u64*)gdst = a0;
            *(u64*)(gdst + 8) = a1;
        }
    }
}

// ---------------- Kernel S: score GEMM + row-max (unchanged, verified) ----------------
__global__ __launch_bounds__(512, 2) void score_kernel(
    const f16* __restrict__ Qh, const char* __restrict__ Ksw, float* __restrict__ rowmax)
{
    __shared__ __align__(16) char kbuf[2][32768];
    __shared__ float lds_rm[256][2];

    const int batch = blockIdx.x & 7;
    const int r0    = (blockIdx.x >> 3) * 256;
    const int tid   = threadIdx.x;
    const int lane  = tid & 63;
    const int wid   = tid >> 6;
    const int wr = wid >> 1, wc = wid & 1;
    const int m = lane & 15, g = lane >> 4;
    const int rbase = r0 + wr * 64;

    const char* kbase = Ksw + (size_t)batch * HWSZ * 512;

#define STAGE(buf, ch)                                                                  \
    {                                                                                   \
        const char* _src = kbase + (ch) * 64 * 512 + tid * 16;                          \
        char* _dst = &kbuf[buf][tid * 16];                                              \
        __builtin_amdgcn_global_load_lds((glob_u32*)(_src),        (lds_u32*)(_dst),        16, 0, 0); \
        __builtin_amdgcn_global_load_lds((glob_u32*)(_src + 8192), (lds_u32*)(_dst + 8192), 16, 0, 0); \
        __builtin_amdgcn_global_load_lds((glob_u32*)(_src + 16384),(lds_u32*)(_dst + 16384),16, 0, 0); \
        __builtin_amdgcn_global_load_lds((glob_u32*)(_src + 24576),(lds_u32*)(_dst + 24576),16, 0, 0); \
    }

    STAGE(0, 0);

    f16x8 a[4][8];
#pragma unroll
    for (int t = 0; t < 4; ++t)
#pragma unroll
        for (int kk = 0; kk < 8; ++kk)
            a[t][kk] = *(const f16x8*)(Qh + (size_t)(rbase + t * 16 + m) * CH + kk * 32 + 8 * g);

    int boff[8][2];
    {
        const int sw = (m & 7) << 4;
#pragma unroll
        for (int kk = 0; kk < 8; ++kk)
#pragma unroll
            for (int u2 = 0; u2 < 2; ++u2) {
                const int col = wc * 32 + u2 * 16 + m;
                boff[kk][u2] = col * 512 + ((kk * 64 + g * 16) ^ sw);
            }
    }

    float rm[4][4];
#pragma unroll
    for (int t = 0; t < 4; ++t)
#pragma unroll
        for (int jj = 0; jj < 4; ++jj) rm[t][jj] = -1e30f;

    __syncthreads();

    int cur = 0;
    for (int ch = 0; ch < 16; ++ch) {
        if (ch < 15) STAGE(cur ^ 1, ch + 1);

        const char* kb = &kbuf[cur][0];
        f32x4 acc[4][2];
        const f32x4 vz = {0.f, 0.f, 0.f, 0.f};
#pragma unroll
        for (int t = 0; t < 4; ++t) { acc[t][0] = vz; acc[t][1] = vz; }

#pragma unroll
        for (int kk = 0; kk < 8; ++kk) {
            f16x8 bfr[2];
            bfr[0] = *(const f16x8*)(kb + boff[kk][0]);
            bfr[1] = *(const f16x8*)(kb + boff[kk][1]);
#pragma unroll
            for (int t = 0; t < 4; ++t) {
                acc[t][0] = __builtin_amdgcn_mfma_f32_16x16x32_f16(a[t][kk], bfr[0], acc[t][0], 0, 0, 0);
                acc[t][1] = __builtin_amdgcn_mfma_f32_16x16x32_f16(a[t][kk], bfr[1], acc[t][1], 0, 0, 0);
            }
        }

#pragma unroll
        for (int t = 0; t < 4; ++t)
#pragma unroll
            for (int jj = 0; jj < 4; ++jj)
                rm[t][jj] = fmaxf(rm[t][jj], fmaxf(acc[t][0][jj], acc[t][1][jj]));

        __syncthreads();
        cur ^= 1;
    }
#undef STAGE

#pragma unroll
    for (int d = 1; d < 16; d <<= 1)
#pragma unroll
        for (int t = 0; t < 4; ++t)
#pragma unroll
            for (int jj = 0; jj < 4; ++jj)
                rm[t][jj] = fmaxf(rm[t][jj], __shfl_xor(rm[t][jj], d, 64));

    if (m == 0) {
#pragma unroll
        for (int t = 0; t < 4; ++t)
#pragma unroll
            for (int jj = 0; jj < 4; ++jj)
                lds_rm[wr * 64 + t * 16 + g * 4 + jj][wc] = rm[t][jj];
    }
    __syncthreads();
    if (tid < 256)
        rowmax[(size_t)(r0 + tid) * BATCH + batch] = fmaxf(lds_rm[tid][0], lds_rm[tid][1]);
}

// ---------------- R1: logits (unchanged) ----------------
__global__ __launch_bounds__(256) void logits_kernel(
    const f16* __restrict__ Qh, const float* __restrict__ kmean,
    const float* __restrict__ rowmax, float* __restrict__ logits)
{
    __shared__ float km[BATCH][CH];
    const int tid = threadIdx.x;
#pragma unroll
    for (int i = 0; i < 8; ++i) km[i][tid] = kmean[i * 256 + tid];
    __syncthreads();

    const int r = blockIdx.x * 256 + tid;
    float acc[8];
#pragma unroll
    for (int b = 0; b < 8; ++b) acc[b] = 0.f;

    const f16x8* q = (const f16x8*)(Qh + (size_t)r * CH);
    for (int c8 = 0; c8 < 32; ++c8) {
        f16x8 qv = q[c8];
        float qf[8];
#pragma unroll
        for (int i = 0; i < 8; ++i) qf[i] = (float)qv[i];
#pragma unroll
        for (int b = 0; b < 8; ++b) {
            float4 k0 = *(const float4*)&km[b][c8 * 8];
            float4 k1 = *(const float4*)&km[b][c8 * 8 + 4];
            acc[b] = fmaf(qf[0], k0.x, acc[b]); acc[b] = fmaf(qf[1], k0.y, acc[b]);
            acc[b] = fmaf(qf[2], k0.z, acc[b]); acc[b] = fmaf(qf[3], k0.w, acc[b]);
            acc[b] = fmaf(qf[4], k1.x, acc[b]); acc[b] = fmaf(qf[5], k1.y, acc[b]);
            acc[b] = fmaf(qf[6], k1.z, acc[b]); acc[b] = fmaf(qf[7], k1.w, acc[b]);
        }
    }
    float lg = 0.f;
#pragma unroll
    for (int b = 0; b < 8; ++b) lg += rowmax[(size_t)r * 8 + b] + acc[b];
    logits[r] = lg * (1.0f / 128.0f);
}

// ---------------- R2: softmax (unchanged) ----------------
__global__ __launch_bounds__(256) void softmax_kernel(const float* __restrict__ logits,
                                                      float* __restrict__ wgt)
{
    const int br = blockIdx.x, tid = threadIdx.x;
    __shared__ float red[256];
    float l[4];
#pragma unroll
    for (int i = 0; i < 4; ++i) l[i] = logits[br * HWSZ + i * 256 + tid];

    float mx = fmaxf(fmaxf(l[0], l[1]), fmaxf(l[2], l[3]));
    red[tid] = mx;
    __syncthreads();
    for (int s = 128; s > 0; s >>= 1) {
        if (tid < s) red[tid] = fmaxf(red[tid], red[tid + s]);
        __syncthreads();
    }
    mx = red[0];
    __syncthreads();

    float e[4], sm = 0.f;
#pragma unroll
    for (int i = 0; i < 4; ++i) { e[i] = expf(l[i] - mx); sm += e[i]; }
    red[tid] = sm;
    __syncthreads();
    for (int s = 128; s > 0; s >>= 1) {
        if (tid < s) red[tid] += red[tid + s];
        __syncthreads();
    }
    const float inv = 1.0f / red[0];
#pragma unroll
    for (int i = 0; i < 4; ++i)
        wgt[br * HWSZ + i * 256 + tid] = e[i] * inv;
}

// ---------------- gate: out = wgt * Y + bo, in-place on d_out ----------------
__global__ __launch_bounds__(256) void gate_kernel(float* __restrict__ out,
                                                   const float* __restrict__ wgt,
                                                   const float* __restrict__ bo)
{
    const size_t idx = ((size_t)blockIdx.x * 256 + threadIdx.x) * 8;
    const int b  = (int)(idx >> 18);
    const int c  = (int)(idx >> 10) & 255;
    const int hw = (int)idx & 1023;

    float4 y0 = *(const float4*)(out + idx);
    float4 y1 = *(const float4*)(out + idx + 4);
    float4 w0 = *(const float4*)(wgt + b * HWSZ + hw);
    float4 w1 = *(const float4*)(wgt + b * HWSZ + hw + 4);
    const float bov = bo[c];

    float4 o0, o1;
    o0.x = fmaf(y0.x, w0.x, bov); o0.y = fmaf(y0.y, w0.y, bov);
    o0.z = fmaf(y0.z, w0.z, bov); o0.w = fmaf(y0.w, w0.w, bov);
    o1.x = fmaf(y1.x, w1.x, bov); o1.y = fmaf(y1.y, w1.y, bov);
    o1.z = fmaf(y1.z, w1.z, bov); o1.w = fmaf(y1.w, w1.w, bov);
    *(float4*)(out + idx)     = o0;
    *(float4*)(out + idx + 4) = o1;
}

extern "C" void kernel_launch(void* const* d_in, const int* in_sizes, int n_in,
                              void* d_out, int out_size, void* d_ws, size_t ws_size,
                              hipStream_t stream)
{
    const float* x  = (const float*)d_in[0];
    const float* Wq = (const float*)d_in[1];
    const float* bq = (const float*)d_in[2];
    const float* Wk = (const float*)d_in[3];
    const float* bk = (const float*)d_in[4];
    const float* Wo = (const float*)d_in[5];
    const float* bo = (const float*)d_in[6];
    float* out = (float*)d_out;

    char* ws = (char*)d_ws;
    f16*   Qh     = (f16*)(ws);                                  // 4 MB
    char*  Ksw    = (char*)(ws + (4 << 20));                     // 4 MB (swizzled f16)
    float* rowmax = (float*)(ws + (8 << 20));                    // 256 KB
    float* kmean  = (float*)(ws + (8 << 20) + (256 << 10));      // 8 KB
    float* xmean  = (float*)(ws + (8 << 20) + (264 << 10));      // 8 KB
    float* logits = (float*)(ws + (8 << 20) + (272 << 10));      // 32 KB
    float* wgt    = (float*)(ws + (8 << 20) + (304 << 10));      // 32 KB

    xmean_kernel  <<<dim3(32),      256, 0, stream>>>(x, xmean);
    kmeanW_kernel <<<dim3(1),       256, 0, stream>>>(Wk, bk, xmean, kmean);
    pgemm_kernel  <<<dim3(256, 3),  256, 0, stream>>>(x, Wq, Wk, Wo, bq, bk, Qh, Ksw, out);
    score_kernel  <<<dim3(256),     512, 0, stream>>>(Qh, Ksw, rowmax);
    logits_kernel <<<dim3(32),      256, 0, stream>>>(Qh, kmean, rowmax, logits);
    softmax_kernel<<<dim3(8),       256, 0, stream>>>(logits, wgt);
    gate_kernel   <<<dim3(1024),    256, 0, stream>>>(out, wgt, bo);
}

// Round 4
// 104.472 us; speedup vs baseline: 2.6784x; 1.0356x over previous
//
#include <hip/hip_runtime.h>

#define BATCH 8
#define CH 256
#define HWSZ 1024
#define BHW 8192

typedef _Float16 f16;
typedef _Float16 f16x4 __attribute__((ext_vector_type(4)));
typedef _Float16 f16x8 __attribute__((ext_vector_type(8)));
typedef float f32x4 __attribute__((ext_vector_type(4)));
typedef unsigned long long u64;
typedef __attribute__((address_space(3))) unsigned int lds_u32;
typedef __attribute__((address_space(1))) const unsigned int glob_u32;

// ---------------- xmean: xmean[b*256+c] = mean over HW of x[b,c,:] ----------------
__global__ __launch_bounds__(256) void xmean_kernel(const float* __restrict__ x,
                                                    float* __restrict__ xmean)
{
    const int row  = blockIdx.x * 16 + (threadIdx.x >> 4);   // [0, 2048)
    const int part = threadIdx.x & 15;
    const float4* p = (const float4*)(x + (size_t)row * HWSZ + part * 64);
    float s = 0.f;
#pragma unroll
    for (int i = 0; i < 16; ++i) { float4 v = p[i]; s += v.x + v.y + v.z + v.w; }
    s += __shfl_xor(s, 1, 64);
    s += __shfl_xor(s, 2, 64);
    s += __shfl_xor(s, 4, 64);
    s += __shfl_xor(s, 8, 64);
    if (part == 0) xmean[row] = s * (1.0f / HWSZ);
}

// ---------------- kmean[b][co] = Wk[co,:] . xmean[b,:] + bk[co]  (exact fp32) ----------------
__global__ __launch_bounds__(256) void kmeanW_kernel(
    const float* __restrict__ Wk, const float* __restrict__ bk,
    const float* __restrict__ xmean, float* __restrict__ kmean)
{
    __shared__ float xm[BATCH * CH];
    const int tid = threadIdx.x;
#pragma unroll
    for (int i = 0; i < 8; ++i) xm[i * 256 + tid] = xmean[i * 256 + tid];
    __syncthreads();

    float acc[8];
#pragma unroll
    for (int b = 0; b < 8; ++b) acc[b] = 0.f;
    const float4* w = (const float4*)(Wk + tid * CH);
    for (int c4 = 0; c4 < 64; ++c4) {
        float4 wv = w[c4];
        float wa[4] = {wv.x, wv.y, wv.z, wv.w};
#pragma unroll
        for (int cc = 0; cc < 4; ++cc)
#pragma unroll
            for (int b = 0; b < 8; ++b)
                acc[b] = fmaf(wa[cc], xm[b * 256 + c4 * 4 + cc], acc[b]);
    }
    const float bkv = bk[tid];
#pragma unroll
    for (int b = 0; b < 8; ++b) kmean[b * 256 + tid] = acc[b] + bkv;
}

// ---------------- pgemm: Q/K/Y projections via f16 MFMA with split-x (K=512) ----------------
__global__ __launch_bounds__(256, 2) void pgemm_kernel(
    const float* __restrict__ x,
    const float* __restrict__ Wq, const float* __restrict__ Wk, const float* __restrict__ Wo,
    const float* __restrict__ bq, const float* __restrict__ bk,
    f16* __restrict__ Qh, char* __restrict__ Ksw, float* __restrict__ Yout)
{
    __shared__ __align__(16) char kbuf[32 * 1024];
    __shared__ __align__(16) float xt[256][36];
    f16* tile = (f16*)&xt[0][0];
    char* tileb = (char*)&xt[0][0];

    const int mb   = blockIdx.y;
    const int pxg0 = blockIdx.x * 32;
    const int b    = pxg0 >> 10;
    const int hw0  = pxg0 & 1023;
    const int tid  = threadIdx.x;
    const int lane = tid & 63;
    const int wid  = tid >> 6;
    const int m = lane & 15, g = lane >> 4;

    {
        const int f4 = tid & 7;
        const int cs = tid >> 3;
#pragma unroll
        for (int pass = 0; pass < 8; ++pass) {
            const int c = pass * 32 + cs;
            float4 v = *(const float4*)(x + ((size_t)b * CH + c) * HWSZ + hw0 + f4 * 4);
            *(float4*)&xt[c][f4 * 4] = v;
        }
    }
    __syncthreads();

    {
        const int px = tid & 31;
        const int q8 = tid >> 5;
        const int sw = (px & 7) << 4;
#pragma unroll
        for (int r = 0; r < 4; ++r) {
            f16x8 hi, lo;
#pragma unroll
            for (int i = 0; i < 8; ++i) {
                const int c = q8 * 32 + r * 8 + i;
                float v = xt[c][px];
                f16 h = (f16)v;
                hi[i] = h;
                lo[i] = (f16)(v - (float)h);
            }
            const int base = q8 * 64 + r * 16;
            *(f16x8*)(kbuf + px * 1024 + (base ^ sw)) = hi;
            *(f16x8*)(kbuf + px * 1024 + 512 + (base ^ sw)) = lo;
        }
    }

    const float* Wsel = (mb == 0) ? Wq : (mb == 1) ? Wk : Wo;
    f16x8 a[4][8];
#pragma unroll
    for (int t = 0; t < 4; ++t)
#pragma unroll
        for (int kk = 0; kk < 8; ++kk) {
            const float* wrow = Wsel + (size_t)(wid * 64 + t * 16 + m) * CH + kk * 32 + g * 8;
            float4 w0 = *(const float4*)(wrow);
            float4 w1 = *(const float4*)(wrow + 4);
            f16x8 av;
            av[0] = (f16)w0.x; av[1] = (f16)w0.y; av[2] = (f16)w0.z; av[3] = (f16)w0.w;
            av[4] = (f16)w1.x; av[5] = (f16)w1.y; av[6] = (f16)w1.z; av[7] = (f16)w1.w;
            a[t][kk] = av;
        }

    __syncthreads();

    f32x4 acc[4][2];
    const f32x4 vz = {0.f, 0.f, 0.f, 0.f};
#pragma unroll
    for (int t = 0; t < 4; ++t) { acc[t][0] = vz; acc[t][1] = vz; }

    const int sw0 = (m & 7) << 4;
#pragma unroll
    for (int ks = 0; ks < 16; ++ks) {
        const int X = ks * 64 + g * 16;
        f16x8 b0 = *(const f16x8*)(kbuf + m * 1024 + (X ^ sw0));
        f16x8 b1 = *(const f16x8*)(kbuf + (16 + m) * 1024 + (X ^ sw0));
#pragma unroll
        for (int t = 0; t < 4; ++t) {
            acc[t][0] = __builtin_amdgcn_mfma_f32_16x16x32_f16(a[t][ks & 7], b0, acc[t][0], 0, 0, 0);
            acc[t][1] = __builtin_amdgcn_mfma_f32_16x16x32_f16(a[t][ks & 7], b1, acc[t][1], 0, 0, 0);
        }
    }

    if (mb == 2) {
#pragma unroll
        for (int t = 0; t < 4; ++t)
#pragma unroll
            for (int u = 0; u < 2; ++u)
#pragma unroll
                for (int j = 0; j < 4; ++j) {
                    const int co = wid * 64 + t * 16 + 4 * g + j;
                    Yout[((size_t)b * CH + co) * HWSZ + hw0 + u * 16 + m] = acc[t][u][j];
                }
        return;
    }

    const float* bias = (mb == 0) ? bq : bk;
    if (mb == 0) {
#pragma unroll
        for (int t = 0; t < 4; ++t) {
            const int co0 = wid * 64 + t * 16 + 4 * g;
            float4 bv = *(const float4*)(bias + co0);
            float ba[4] = {bv.x, bv.y, bv.z, bv.w};
#pragma unroll
            for (int u = 0; u < 2; ++u) {
                const int px = u * 16 + m;
#pragma unroll
                for (int j = 0; j < 4; ++j)
                    tile[(co0 + j) * 32 + (px ^ (j << 3))] = (f16)(acc[t][u][j] + ba[j]);
            }
        }
        __syncthreads();
#pragma unroll
        for (int pass = 0; pass < 4; ++pass) {
            const int co  = pass * 64 + (tid >> 2);
            const int run = tid & 3;
            f16x8 v = *(const f16x8*)(tile + co * 32 + ((run * 8) ^ ((co & 3) << 3)));
            *(f16x8*)(Qh + ((size_t)b * CH + co) * HWSZ + hw0 + run * 8) = v;
        }
    } else {
#pragma unroll
        for (int t = 0; t < 4; ++t) {
            const int co0 = wid * 64 + t * 16 + 4 * g;
            float4 bv = *(const float4*)(bias + co0);
            float ba[4] = {bv.x, bv.y, bv.z, bv.w};
#pragma unroll
            for (int u = 0; u < 2; ++u) {
                const int px = u * 16 + m;
                f16x4 pk;
#pragma unroll
                for (int j = 0; j < 4; ++j) pk[j] = (f16)(acc[t][u][j] + ba[j]);
                *(f16x4*)(tileb + px * 512 + ((co0 * 2) ^ (m << 3))) = pk;
            }
        }
        __syncthreads();
        const int px = tid & 31;
        const int rp = tid >> 5;
        const int kloc = (px & 15) << 3;
        const int kglb = (px & 7) << 4;
        char* grow = Ksw + (size_t)(pxg0 + px) * 512;
#pragma unroll
        for (int i = 0; i < 4; ++i) {
            const int r = rp + i * 8;
            u64 a0 = *(const u64*)(tileb + px * 512 + ((r * 16) ^ kloc));
            u64 a1 = *(const u64*)(tileb + px * 512 + ((r * 16 + 8) ^ kloc));
            char* gdst = grow + ((r * 16) ^ kglb);
            *(u64*)gdst = a0;
            *(u64*)(gdst + 8) = a1;
        }
    }
}

// ---------------- Kernel S: score GEMM + row-max, 128 rows/block, 2 blocks/CU ----------------
// grid 512: batch = bid&7 (XCD-affine), rowblock = bid>>3 (128 rows).
// 8 waves: wr=wid>>1 -> 32 rows, wc=wid&1 -> 32 of 64 staged cols.
__global__ __launch_bounds__(512, 4) void score_kernel(
    const f16* __restrict__ Qh, const char* __restrict__ Ksw, float* __restrict__ rowmax)
{
    __shared__ __align__(16) char kbuf[2][32768];   // 64 cols x 512B, double buffered
    __shared__ float lds_rm[128][2];

    const int batch = blockIdx.x & 7;
    const int r0    = (blockIdx.x >> 3) * 128;
    const int tid   = threadIdx.x;
    const int lane  = tid & 63;
    const int wid   = tid >> 6;
    const int wr = wid >> 1, wc = wid & 1;
    const int m = lane & 15, g = lane >> 4;
    const int rbase = r0 + wr * 32;

    const char* kbase = Ksw + (size_t)batch * HWSZ * 512;

#define STAGE(buf, ch)                                                                  \
    {                                                                                   \
        const char* _src = kbase + (ch) * 64 * 512 + tid * 16;                          \
        char* _dst = &kbuf[buf][tid * 16];                                              \
        __builtin_amdgcn_global_load_lds((glob_u32*)(_src),        (lds_u32*)(_dst),        16, 0, 0); \
        __builtin_amdgcn_global_load_lds((glob_u32*)(_src + 8192), (lds_u32*)(_dst + 8192), 16, 0, 0); \
        __builtin_amdgcn_global_load_lds((glob_u32*)(_src + 16384),(lds_u32*)(_dst + 16384),16, 0, 0); \
        __builtin_amdgcn_global_load_lds((glob_u32*)(_src + 24576),(lds_u32*)(_dst + 24576),16, 0, 0); \
    }

    STAGE(0, 0);

    // A fragments: 32 rows x K=256 in registers.
    f16x8 a[2][8];
#pragma unroll
    for (int t = 0; t < 2; ++t)
#pragma unroll
        for (int kk = 0; kk < 8; ++kk)
            a[t][kk] = *(const f16x8*)(Qh + (size_t)(rbase + t * 16 + m) * CH + kk * 32 + 8 * g);

    // Precomputed swizzled B offsets (chunk-invariant).
    int boff[8][2];
    {
        const int sw = (m & 7) << 4;
#pragma unroll
        for (int kk = 0; kk < 8; ++kk)
#pragma unroll
            for (int u2 = 0; u2 < 2; ++u2) {
                const int col = wc * 32 + u2 * 16 + m;
                boff[kk][u2] = col * 512 + ((kk * 64 + g * 16) ^ sw);
            }
    }

    float rm[2][4];
#pragma unroll
    for (int t = 0; t < 2; ++t)
#pragma unroll
        for (int jj = 0; jj < 4; ++jj) rm[t][jj] = -1e30f;

    __syncthreads();   // chunk 0 staged

    int cur = 0;
    for (int ch = 0; ch < 16; ++ch) {
        if (ch < 15) STAGE(cur ^ 1, ch + 1);

        const char* kb = &kbuf[cur][0];
        f32x4 acc[2][2];
        const f32x4 vz = {0.f, 0.f, 0.f, 0.f};
#pragma unroll
        for (int t = 0; t < 2; ++t) { acc[t][0] = vz; acc[t][1] = vz; }

#pragma unroll
        for (int kk = 0; kk < 8; ++kk) {
            f16x8 bfr[2];
            bfr[0] = *(const f16x8*)(kb + boff[kk][0]);
            bfr[1] = *(const f16x8*)(kb + boff[kk][1]);
#pragma unroll
            for (int t = 0; t < 2; ++t) {
                acc[t][0] = __builtin_amdgcn_mfma_f32_16x16x32_f16(a[t][kk], bfr[0], acc[t][0], 0, 0, 0);
                acc[t][1] = __builtin_amdgcn_mfma_f32_16x16x32_f16(a[t][kk], bfr[1], acc[t][1], 0, 0, 0);
            }
        }

#pragma unroll
        for (int t = 0; t < 2; ++t)
#pragma unroll
            for (int jj = 0; jj < 4; ++jj)
                rm[t][jj] = fmaxf(rm[t][jj], fmaxf(acc[t][0][jj], acc[t][1][jj]));

        __syncthreads();
        cur ^= 1;
    }
#undef STAGE

#pragma unroll
    for (int d = 1; d < 16; d <<= 1)
#pragma unroll
        for (int t = 0; t < 2; ++t)
#pragma unroll
            for (int jj = 0; jj < 4; ++jj)
                rm[t][jj] = fmaxf(rm[t][jj], __shfl_xor(rm[t][jj], d, 64));

    if (m == 0) {
#pragma unroll
        for (int t = 0; t < 2; ++t)
#pragma unroll
            for (int jj = 0; jj < 4; ++jj)
                lds_rm[wr * 32 + t * 16 + g * 4 + jj][wc] = rm[t][jj];
    }
    __syncthreads();
    if (tid < 128)
        rowmax[(size_t)(r0 + tid) * BATCH + batch] = fmaxf(lds_rm[tid][0], lds_rm[tid][1]);
}

// ---------------- R1: logits ----------------
__global__ __launch_bounds__(256) void logits_kernel(
    const f16* __restrict__ Qh, const float* __restrict__ kmean,
    const float* __restrict__ rowmax, float* __restrict__ logits)
{
    __shared__ float km[BATCH][CH];
    const int tid = threadIdx.x;
#pragma unroll
    for (int i = 0; i < 8; ++i) km[i][tid] = kmean[i * 256 + tid];
    __syncthreads();

    const int r = blockIdx.x * 256 + tid;
    float acc[8];
#pragma unroll
    for (int b = 0; b < 8; ++b) acc[b] = 0.f;

    const f16x8* q = (const f16x8*)(Qh + (size_t)r * CH);
    for (int c8 = 0; c8 < 32; ++c8) {
        f16x8 qv = q[c8];
        float qf[8];
#pragma unroll
        for (int i = 0; i < 8; ++i) qf[i] = (float)qv[i];
#pragma unroll
        for (int b = 0; b < 8; ++b) {
            float4 k0 = *(const float4*)&km[b][c8 * 8];
            float4 k1 = *(const float4*)&km[b][c8 * 8 + 4];
            acc[b] = fmaf(qf[0], k0.x, acc[b]); acc[b] = fmaf(qf[1], k0.y, acc[b]);
            acc[b] = fmaf(qf[2], k0.z, acc[b]); acc[b] = fmaf(qf[3], k0.w, acc[b]);
            acc[b] = fmaf(qf[4], k1.x, acc[b]); acc[b] = fmaf(qf[5], k1.y, acc[b]);
            acc[b] = fmaf(qf[6], k1.z, acc[b]); acc[b] = fmaf(qf[7], k1.w, acc[b]);
        }
    }
    float lg = 0.f;
#pragma unroll
    for (int b = 0; b < 8; ++b) lg += rowmax[(size_t)r * 8 + b] + acc[b];
    logits[r] = lg * (1.0f / 128.0f);
}

// ---------------- R2: softmax over HW per batch ----------------
__global__ __launch_bounds__(256) void softmax_kernel(const float* __restrict__ logits,
                                                      float* __restrict__ wgt)
{
    const int br = blockIdx.x, tid = threadIdx.x;
    __shared__ float red[256];
    float l[4];
#pragma unroll
    for (int i = 0; i < 4; ++i) l[i] = logits[br * HWSZ + i * 256 + tid];

    float mx = fmaxf(fmaxf(l[0], l[1]), fmaxf(l[2], l[3]));
    red[tid] = mx;
    __syncthreads();
    for (int s = 128; s > 0; s >>= 1) {
        if (tid < s) red[tid] = fmaxf(red[tid], red[tid + s]);
        __syncthreads();
    }
    mx = red[0];
    __syncthreads();

    float e[4], sm = 0.f;
#pragma unroll
    for (int i = 0; i < 4; ++i) { e[i] = expf(l[i] - mx); sm += e[i]; }
    red[tid] = sm;
    __syncthreads();
    for (int s = 128; s > 0; s >>= 1) {
        if (tid < s) red[tid] += red[tid + s];
        __syncthreads();
    }
    const float inv = 1.0f / red[0];
#pragma unroll
    for (int i = 0; i < 4; ++i)
        wgt[br * HWSZ + i * 256 + tid] = e[i] * inv;
}

// ---------------- gate: out = wgt * Y + bo, in-place on d_out ----------------
__global__ __launch_bounds__(256) void gate_kernel(float* __restrict__ out,
                                                   const float* __restrict__ wgt,
                                                   const float* __restrict__ bo)
{
    const size_t idx = ((size_t)blockIdx.x * 256 + threadIdx.x) * 8;
    const int b  = (int)(idx >> 18);
    const int c  = (int)(idx >> 10) & 255;
    const int hw = (int)idx & 1023;

    float4 y0 = *(const float4*)(out + idx);
    float4 y1 = *(const float4*)(out + idx + 4);
    float4 w0 = *(const float4*)(wgt + b * HWSZ + hw);
    float4 w1 = *(const float4*)(wgt + b * HWSZ + hw + 4);
    const float bov = bo[c];

    float4 o0, o1;
    o0.x = fmaf(y0.x, w0.x, bov); o0.y = fmaf(y0.y, w0.y, bov);
    o0.z = fmaf(y0.z, w0.z, bov); o0.w = fmaf(y0.w, w0.w, bov);
    o1.x = fmaf(y1.x, w1.x, bov); o1.y = fmaf(y1.y, w1.y, bov);
    o1.z = fmaf(y1.z, w1.z, bov); o1.w = fmaf(y1.w, w1.w, bov);
    *(float4*)(out + idx)     = o0;
    *(float4*)(out + idx + 4) = o1;
}

extern "C" void kernel_launch(void* const* d_in, const int* in_sizes, int n_in,
                              void* d_out, int out_size, void* d_ws, size_t ws_size,
                              hipStream_t stream)
{
    const float* x  = (const float*)d_in[0];
    const float* Wq = (const float*)d_in[1];
    const float* bq = (const float*)d_in[2];
    const float* Wk = (const float*)d_in[3];
    const float* bk = (const float*)d_in[4];
    const float* Wo = (const float*)d_in[5];
    const float* bo = (const float*)d_in[6];
    float* out = (float*)d_out;

    char* ws = (char*)d_ws;
    f16*   Qh     = (f16*)(ws);                                  // 4 MB
    char*  Ksw    = (char*)(ws + (4 << 20));                     // 4 MB (swizzled f16)
    float* rowmax = (float*)(ws + (8 << 20));                    // 256 KB
    float* kmean  = (float*)(ws + (8 << 20) + (256 << 10));      // 8 KB
    float* xmean  = (float*)(ws + (8 << 20) + (264 << 10));      // 8 KB
    float* logits = (float*)(ws + (8 << 20) + (272 << 10));      // 32 KB
    float* wgt    = (float*)(ws + (8 << 20) + (304 << 10));      // 32 KB

    xmean_kernel  <<<dim3(128),     256, 0, stream>>>(x, xmean);
    kmeanW_kernel <<<dim3(1),       256, 0, stream>>>(Wk, bk, xmean, kmean);
    pgemm_kernel  <<<dim3(256, 3),  256, 0, stream>>>(x, Wq, Wk, Wo, bq, bk, Qh, Ksw, out);
    score_kernel  <<<dim3(512),     512, 0, stream>>>(Qh, Ksw, rowmax);
    logits_kernel <<<dim3(32),      256, 0, stream>>>(Qh, kmean, rowmax, logits);
    softmax_kernel<<<dim3(8),       256, 0, stream>>>(logits, wgt);
    gate_kernel   <<<dim3(1024),    256, 0, stream>>>(out, wgt, bo);
}

// Round 5
// 102.719 us; speedup vs baseline: 2.7241x; 1.0171x over previous
//
#include <hip/hip_runtime.h>

#define BATCH 8
#define CH 256
#define HWSZ 1024
#define BHW 8192

typedef _Float16 f16;
typedef _Float16 f16x4 __attribute__((ext_vector_type(4)));
typedef _Float16 f16x8 __attribute__((ext_vector_type(8)));
typedef float f32x4 __attribute__((ext_vector_type(4)));
typedef unsigned long long u64;
typedef __attribute__((address_space(3))) unsigned int lds_u32;
typedef __attribute__((address_space(1))) const unsigned int glob_u32;

// ---------------- xmean: xmean[b*256+c] = mean over HW of x[b,c,:] ----------------
__global__ __launch_bounds__(256) void xmean_kernel(const float* __restrict__ x,
                                                    float* __restrict__ xmean)
{
    const int row  = blockIdx.x * 8 + (threadIdx.x >> 5);    // [0, 2048)
    const int part = threadIdx.x & 31;
    const float4* p = (const float4*)(x + (size_t)row * HWSZ);
    float s = 0.f;
#pragma unroll
    for (int i = 0; i < 8; ++i) { float4 v = p[i * 32 + part]; s += v.x + v.y + v.z + v.w; }
    s += __shfl_xor(s, 1, 64);
    s += __shfl_xor(s, 2, 64);
    s += __shfl_xor(s, 4, 64);
    s += __shfl_xor(s, 8, 64);
    s += __shfl_xor(s, 16, 64);
    if (part == 0) xmean[row] = s * (1.0f / HWSZ);
}

// ---------------- kmean[b][co] = Wk[co,:] . xmean[b,:] + bk[co]  (exact fp32) ----------------
__global__ __launch_bounds__(256) void kmeanW_kernel(
    const float* __restrict__ Wk, const float* __restrict__ bk,
    const float* __restrict__ xmean, float* __restrict__ kmean)
{
    __shared__ float xm[CH];
    const int b = blockIdx.x;
    const int tid = threadIdx.x;
    xm[tid] = xmean[b * 256 + tid];
    __syncthreads();

    float acc = 0.f;
    const float4* w = (const float4*)(Wk + tid * CH);
    for (int c4 = 0; c4 < 64; ++c4) {
        float4 wv = w[c4];
        acc = fmaf(wv.x, xm[c4 * 4 + 0], acc);
        acc = fmaf(wv.y, xm[c4 * 4 + 1], acc);
        acc = fmaf(wv.z, xm[c4 * 4 + 2], acc);
        acc = fmaf(wv.w, xm[c4 * 4 + 3], acc);
    }
    kmean[b * 256 + tid] = acc + bk[tid];
}

// ---------------- pgemmQK: Q and K projections, one x-tile pass, f16 MFMA split-x ----------------
// 512 threads = 8 waves; wave owns 32 co rows (t=2); 32 px/block; grid 256.
__global__ __launch_bounds__(512, 1) void pgemmQK_kernel(
    const float* __restrict__ x,
    const float* __restrict__ Wq, const float* __restrict__ Wk,
    const float* __restrict__ bq, const float* __restrict__ bk,
    f16* __restrict__ Qh, char* __restrict__ Ksw)
{
    __shared__ __align__(16) char kbuf[32 * 1024];     // x^T split tile (hi|lo per px)
    __shared__ __align__(16) float xt[256][36];        // fp32 staging; reused as epilogue bounce
    f16* tile = (f16*)&xt[0][0];
    char* tileb = (char*)&xt[0][0];

    const int pxg0 = blockIdx.x * 32;
    const int b    = pxg0 >> 10;
    const int hw0  = pxg0 & 1023;
    const int tid  = threadIdx.x;
    const int lane = tid & 63;
    const int wid  = tid >> 6;
    const int m = lane & 15, g = lane >> 4;

    // Phase A: coalesced load of x[b][0..255][hw0..+32)
    {
        const int f4 = tid & 7;
        const int cs = tid >> 3;           // [0,64)
#pragma unroll
        for (int pass = 0; pass < 4; ++pass) {
            const int c = pass * 64 + cs;
            float4 v = *(const float4*)(x + ((size_t)b * CH + c) * HWSZ + hw0 + f4 * 4);
            *(float4*)&xt[c][f4 * 4] = v;
        }
    }
    __syncthreads();

    // Phase B: transpose + hi/lo split into kbuf
    {
        const int px = tid & 31;
        const int q8 = tid >> 5;           // [0,16)
        const int sw = (px & 7) << 4;
#pragma unroll
        for (int r = 0; r < 2; ++r) {
            f16x8 hi, lo;
#pragma unroll
            for (int i = 0; i < 8; ++i) {
                const int c = q8 * 16 + r * 8 + i;
                float v = xt[c][px];
                f16 h = (f16)v;
                hi[i] = h;
                lo[i] = (f16)(v - (float)h);
            }
            const int base = q8 * 32 + r * 16;
            *(f16x8*)(kbuf + px * 1024 + (base ^ sw)) = hi;
            *(f16x8*)(kbuf + px * 1024 + 512 + (base ^ sw)) = lo;
        }
    }

    // Wq A-frags
    f16x8 a[2][8];
#define LOAD_W(Wsel)                                                                     \
    {                                                                                    \
        _Pragma("unroll")                                                                \
        for (int t = 0; t < 2; ++t)                                                      \
            _Pragma("unroll")                                                            \
            for (int kk = 0; kk < 8; ++kk) {                                             \
                const float* wrow = (Wsel) + (size_t)(wid * 32 + t * 16 + m) * CH + kk * 32 + g * 8; \
                float4 w0 = *(const float4*)(wrow);                                      \
                float4 w1 = *(const float4*)(wrow + 4);                                  \
                f16x8 av;                                                                \
                av[0] = (f16)w0.x; av[1] = (f16)w0.y; av[2] = (f16)w0.z; av[3] = (f16)w0.w; \
                av[4] = (f16)w1.x; av[5] = (f16)w1.y; av[6] = (f16)w1.z; av[7] = (f16)w1.w; \
                a[t][kk] = av;                                                           \
            }                                                                            \
    }
    LOAD_W(Wq);
    __syncthreads();   // kbuf ready, xt free

    const int sw0 = (m & 7) << 4;
    const f32x4 vz = {0.f, 0.f, 0.f, 0.f};
    f32x4 acc[2][2];

#define MFMA_PASS()                                                                      \
    {                                                                                    \
        _Pragma("unroll")                                                                \
        for (int t = 0; t < 2; ++t) { acc[t][0] = vz; acc[t][1] = vz; }                  \
        _Pragma("unroll")                                                                \
        for (int ks = 0; ks < 16; ++ks) {                                                \
            const int X = ks * 64 + g * 16;                                              \
            f16x8 b0 = *(const f16x8*)(kbuf + m * 1024 + (X ^ sw0));                     \
            f16x8 b1 = *(const f16x8*)(kbuf + (16 + m) * 1024 + (X ^ sw0));              \
            _Pragma("unroll")                                                            \
            for (int t = 0; t < 2; ++t) {                                                \
                acc[t][0] = __builtin_amdgcn_mfma_f32_16x16x32_f16(a[t][ks & 7], b0, acc[t][0], 0, 0, 0); \
                acc[t][1] = __builtin_amdgcn_mfma_f32_16x16x32_f16(a[t][ks & 7], b1, acc[t][1], 0, 0, 0); \
            }                                                                            \
        }                                                                                \
    }

    // ---- Q pass ----
    MFMA_PASS();

    // Q epilogue: bounce to LDS, coalesced f16x8 stores
#pragma unroll
    for (int t = 0; t < 2; ++t) {
        const int co0 = wid * 32 + t * 16 + 4 * g;
        float4 bv = *(const float4*)(bq + co0);
        float ba[4] = {bv.x, bv.y, bv.z, bv.w};
#pragma unroll
        for (int u = 0; u < 2; ++u) {
            const int px = u * 16 + m;
#pragma unroll
            for (int j = 0; j < 4; ++j)
                tile[(co0 + j) * 32 + (px ^ (j << 3))] = (f16)(acc[t][u][j] + ba[j]);
        }
    }
    __syncthreads();   // tile written
#pragma unroll
    for (int pass = 0; pass < 2; ++pass) {
        const int co  = pass * 128 + (tid >> 2);
        const int run = tid & 3;
        f16x8 v = *(const f16x8*)(tile + co * 32 + ((run * 8) ^ ((co & 3) << 3)));
        *(f16x8*)(Qh + ((size_t)b * CH + co) * HWSZ + hw0 + run * 8) = v;
    }

    // ---- K pass ----
    LOAD_W(Wk);
    MFMA_PASS();
    __syncthreads();   // Q tile reads complete before K overwrites

#pragma unroll
    for (int t = 0; t < 2; ++t) {
        const int co0 = wid * 32 + t * 16 + 4 * g;
        float4 bv = *(const float4*)(bk + co0);
        float ba[4] = {bv.x, bv.y, bv.z, bv.w};
#pragma unroll
        for (int u = 0; u < 2; ++u) {
            const int px = u * 16 + m;
            f16x4 pk;
#pragma unroll
            for (int j = 0; j < 4; ++j) pk[j] = (f16)(acc[t][u][j] + ba[j]);
            *(f16x4*)(tileb + px * 512 + ((co0 * 2) ^ (m << 3)));
            *(f16x4*)(tileb + px * 512 + ((co0 * 2) ^ (m << 3))) = pk;
        }
    }
    __syncthreads();
    {
        const int px = tid & 31;
        const int rp = tid >> 5;           // [0,16)
        const int kloc = (px & 15) << 3;
        const int kglb = (px & 7) << 4;
        char* grow = Ksw + (size_t)(pxg0 + px) * 512;
#pragma unroll
        for (int i = 0; i < 2; ++i) {
            const int r = rp + i * 16;
            u64 a0 = *(const u64*)(tileb + px * 512 + ((r * 16) ^ kloc));
            u64 a1 = *(const u64*)(tileb + px * 512 + ((r * 16 + 8) ^ kloc));
            char* gdst = grow + ((r * 16) ^ kglb);
            *(u64*)gdst = a0;
            *(u64*)(gdst + 8) = a1;
        }
    }
#undef MFMA_PASS
#undef LOAD_W
}

// ---------------- score: 128 rows x 1024 cols per 256-thread block, t=4, 2 blocks/CU ----------------
__global__ __launch_bounds__(256, 2) void score_kernel(
    const f16* __restrict__ Qh, const char* __restrict__ Ksw, float* __restrict__ rowmax)
{
    __shared__ __align__(16) char kbuf[2][32768];   // 64 cols x 512B, double buffered
    __shared__ float lds_rm[128][2];

    const int batch = blockIdx.x & 7;
    const int r0    = (blockIdx.x >> 3) * 128;
    const int tid   = threadIdx.x;
    const int lane  = tid & 63;
    const int wid   = tid >> 6;          // 4 waves
    const int wr = wid >> 1, wc = wid & 1;
    const int m = lane & 15, g = lane >> 4;
    const int rbase = r0 + wr * 64;

    const char* kbase = Ksw + (size_t)batch * HWSZ * 512;

#define STAGE(buf, ch)                                                                   \
    {                                                                                    \
        const char* _src = kbase + (ch) * 64 * 512 + tid * 16;                           \
        char* _dst = &kbuf[buf][tid * 16];                                               \
        _Pragma("unroll")                                                                \
        for (int k = 0; k < 8; ++k)                                                      \
            __builtin_amdgcn_global_load_lds((glob_u32*)(_src + k * 4096),               \
                                             (lds_u32*)(_dst + k * 4096), 16, 0, 0);     \
    }

    STAGE(0, 0);

    // A fragments: 64 rows x K=256 in registers (128 VGPR)
    f16x8 a[4][8];
#pragma unroll
    for (int t = 0; t < 4; ++t)
#pragma unroll
        for (int kk = 0; kk < 8; ++kk)
            a[t][kk] = *(const f16x8*)(Qh + (size_t)(rbase + t * 16 + m) * CH + kk * 32 + 8 * g);

    int boff[8][2];
    {
        const int sw = (m & 7) << 4;
#pragma unroll
        for (int kk = 0; kk < 8; ++kk)
#pragma unroll
            for (int u2 = 0; u2 < 2; ++u2) {
                const int col = wc * 32 + u2 * 16 + m;
                boff[kk][u2] = col * 512 + ((kk * 64 + g * 16) ^ sw);
            }
    }

    float rm[4][4];
#pragma unroll
    for (int t = 0; t < 4; ++t)
#pragma unroll
        for (int jj = 0; jj < 4; ++jj) rm[t][jj] = -1e30f;

    __syncthreads();   // chunk 0 staged

    int cur = 0;
    for (int ch = 0; ch < 16; ++ch) {
        if (ch < 15) STAGE(cur ^ 1, ch + 1);

        const char* kb = &kbuf[cur][0];
        f32x4 acc[4][2];
        const f32x4 vz = {0.f, 0.f, 0.f, 0.f};
#pragma unroll
        for (int t = 0; t < 4; ++t) { acc[t][0] = vz; acc[t][1] = vz; }

#pragma unroll
        for (int kk = 0; kk < 8; ++kk) {
            f16x8 bfr[2];
            bfr[0] = *(const f16x8*)(kb + boff[kk][0]);
            bfr[1] = *(const f16x8*)(kb + boff[kk][1]);
#pragma unroll
            for (int t = 0; t < 4; ++t) {
                acc[t][0] = __builtin_amdgcn_mfma_f32_16x16x32_f16(a[t][kk], bfr[0], acc[t][0], 0, 0, 0);
                acc[t][1] = __builtin_amdgcn_mfma_f32_16x16x32_f16(a[t][kk], bfr[1], acc[t][1], 0, 0, 0);
            }
        }

#pragma unroll
        for (int t = 0; t < 4; ++t)
#pragma unroll
            for (int jj = 0; jj < 4; ++jj)
                rm[t][jj] = fmaxf(rm[t][jj], fmaxf(acc[t][0][jj], acc[t][1][jj]));

        __syncthreads();
        cur ^= 1;
    }
#undef STAGE

#pragma unroll
    for (int d = 1; d < 16; d <<= 1)
#pragma unroll
        for (int t = 0; t < 4; ++t)
#pragma unroll
            for (int jj = 0; jj < 4; ++jj)
                rm[t][jj] = fmaxf(rm[t][jj], __shfl_xor(rm[t][jj], d, 64));

    if (m == 0) {
#pragma unroll
        for (int t = 0; t < 4; ++t)
#pragma unroll
            for (int jj = 0; jj < 4; ++jj)
                lds_rm[wr * 64 + t * 16 + g * 4 + jj][wc] = rm[t][jj];
    }
    __syncthreads();
    if (tid < 128)
        rowmax[(size_t)(r0 + tid) * BATCH + batch] = fmaxf(lds_rm[tid][0], lds_rm[tid][1]);
}

// ---------------- logits ----------------
__global__ __launch_bounds__(256) void logits_kernel(
    const f16* __restrict__ Qh, const float* __restrict__ kmean,
    const float* __restrict__ rowmax, float* __restrict__ logits)
{
    __shared__ float km[BATCH][CH];
    const int tid = threadIdx.x;
#pragma unroll
    for (int i = 0; i < 8; ++i) km[i][tid] = kmean[i * 256 + tid];
    __syncthreads();

    const int r = blockIdx.x * 256 + tid;
    float acc[8];
#pragma unroll
    for (int b = 0; b < 8; ++b) acc[b] = 0.f;

    const f16x8* q = (const f16x8*)(Qh + (size_t)r * CH);
    for (int c8 = 0; c8 < 32; ++c8) {
        f16x8 qv = q[c8];
        float qf[8];
#pragma unroll
        for (int i = 0; i < 8; ++i) qf[i] = (float)qv[i];
#pragma unroll
        for (int b = 0; b < 8; ++b) {
            float4 k0 = *(const float4*)&km[b][c8 * 8];
            float4 k1 = *(const float4*)&km[b][c8 * 8 + 4];
            acc[b] = fmaf(qf[0], k0.x, acc[b]); acc[b] = fmaf(qf[1], k0.y, acc[b]);
            acc[b] = fmaf(qf[2], k0.z, acc[b]); acc[b] = fmaf(qf[3], k0.w, acc[b]);
            acc[b] = fmaf(qf[4], k1.x, acc[b]); acc[b] = fmaf(qf[5], k1.y, acc[b]);
            acc[b] = fmaf(qf[6], k1.z, acc[b]); acc[b] = fmaf(qf[7], k1.w, acc[b]);
        }
    }
    float lg = 0.f;
#pragma unroll
    for (int b = 0; b < 8; ++b) lg += rowmax[(size_t)r * 8 + b] + acc[b];
    logits[r] = lg * (1.0f / 128.0f);
}

// ---------------- softmax over HW per batch ----------------
__global__ __launch_bounds__(256) void softmax_kernel(const float* __restrict__ logits,
                                                      float* __restrict__ wgt)
{
    const int br = blockIdx.x, tid = threadIdx.x;
    __shared__ float red[256];
    float l[4];
#pragma unroll
    for (int i = 0; i < 4; ++i) l[i] = logits[br * HWSZ + i * 256 + tid];

    float mx = fmaxf(fmaxf(l[0], l[1]), fmaxf(l[2], l[3]));
    red[tid] = mx;
    __syncthreads();
    for (int s = 128; s > 0; s >>= 1) {
        if (tid < s) red[tid] = fmaxf(red[tid], red[tid + s]);
        __syncthreads();
    }
    mx = red[0];
    __syncthreads();

    float e[4], sm = 0.f;
#pragma unroll
    for (int i = 0; i < 4; ++i) { e[i] = expf(l[i] - mx); sm += e[i]; }
    red[tid] = sm;
    __syncthreads();
    for (int s = 128; s > 0; s >>= 1) {
        if (tid < s) red[tid] += red[tid + s];
        __syncthreads();
    }
    const float inv = 1.0f / red[0];
#pragma unroll
    for (int i = 0; i < 4; ++i)
        wgt[br * HWSZ + i * 256 + tid] = e[i] * inv;
}

// ---------------- pgemmY: out = wgt * (Wo @ x) + bo, hi-only f16 MFMA, gate fused ----------------
__global__ __launch_bounds__(512, 1) void pgemmY_kernel(
    const float* __restrict__ x, const float* __restrict__ Wo, const float* __restrict__ bo,
    const float* __restrict__ wgt, float* __restrict__ out)
{
    __shared__ __align__(16) char kbuf[16 * 1024];     // hi-only x^T tile
    __shared__ __align__(16) float xt[256][36];

    const int pxg0 = blockIdx.x * 32;
    const int b    = pxg0 >> 10;
    const int hw0  = pxg0 & 1023;
    const int tid  = threadIdx.x;
    const int lane = tid & 63;
    const int wid  = tid >> 6;
    const int m = lane & 15, g = lane >> 4;

    {
        const int f4 = tid & 7;
        const int cs = tid >> 3;
#pragma unroll
        for (int pass = 0; pass < 4; ++pass) {
            const int c = pass * 64 + cs;
            float4 v = *(const float4*)(x + ((size_t)b * CH + c) * HWSZ + hw0 + f4 * 4);
            *(float4*)&xt[c][f4 * 4] = v;
        }
    }
    __syncthreads();

    {
        const int px = tid & 31;
        const int q8 = tid >> 5;
        const int sw = (px & 7) << 4;
#pragma unroll
        for (int r = 0; r < 2; ++r) {
            f16x8 hi;
#pragma unroll
            for (int i = 0; i < 8; ++i)
                hi[i] = (f16)xt[q8 * 16 + r * 8 + i][px];
            *(f16x8*)(kbuf + px * 512 + ((q8 * 32 + r * 16) ^ sw)) = hi;
        }
    }

    f16x8 a[2][8];
#pragma unroll
    for (int t = 0; t < 2; ++t)
#pragma unroll
        for (int kk = 0; kk < 8; ++kk) {
            const float* wrow = Wo + (size_t)(wid * 32 + t * 16 + m) * CH + kk * 32 + g * 8;
            float4 w0 = *(const float4*)(wrow);
            float4 w1 = *(const float4*)(wrow + 4);
            f16x8 av;
            av[0] = (f16)w0.x; av[1] = (f16)w0.y; av[2] = (f16)w0.z; av[3] = (f16)w0.w;
            av[4] = (f16)w1.x; av[5] = (f16)w1.y; av[6] = (f16)w1.z; av[7] = (f16)w1.w;
            a[t][kk] = av;
        }

    __syncthreads();

    f32x4 acc[2][2];
    const f32x4 vz = {0.f, 0.f, 0.f, 0.f};
#pragma unroll
    for (int t = 0; t < 2; ++t) { acc[t][0] = vz; acc[t][1] = vz; }

    const int sw0 = (m & 7) << 4;
#pragma unroll
    for (int ks = 0; ks < 8; ++ks) {
        const int X = ks * 64 + g * 16;
        f16x8 b0 = *(const f16x8*)(kbuf + m * 512 + (X ^ sw0));
        f16x8 b1 = *(const f16x8*)(kbuf + (16 + m) * 512 + (X ^ sw0));
#pragma unroll
        for (int t = 0; t < 2; ++t) {
            acc[t][0] = __builtin_amdgcn_mfma_f32_16x16x32_f16(a[t][ks], b0, acc[t][0], 0, 0, 0);
            acc[t][1] = __builtin_amdgcn_mfma_f32_16x16x32_f16(a[t][ks], b1, acc[t][1], 0, 0, 0);
        }
    }

    // epilogue: gate + bias, direct fp32 stores
    float wv[2];
    wv[0] = wgt[b * HWSZ + hw0 + m];
    wv[1] = wgt[b * HWSZ + hw0 + 16 + m];
#pragma unroll
    for (int t = 0; t < 2; ++t) {
        const int co0 = wid * 32 + t * 16 + 4 * g;
        float4 bv = *(const float4*)(bo + co0);
        float ba[4] = {bv.x, bv.y, bv.z, bv.w};
#pragma unroll
        for (int u = 0; u < 2; ++u)
#pragma unroll
            for (int j = 0; j < 4; ++j)
                out[((size_t)b * CH + co0 + j) * HWSZ + hw0 + u * 16 + m] =
                    fmaf(acc[t][u][j], wv[u], ba[j]);
    }
}

extern "C" void kernel_launch(void* const* d_in, const int* in_sizes, int n_in,
                              void* d_out, int out_size, void* d_ws, size_t ws_size,
                              hipStream_t stream)
{
    const float* x  = (const float*)d_in[0];
    const float* Wq = (const float*)d_in[1];
    const float* bq = (const float*)d_in[2];
    const float* Wk = (const float*)d_in[3];
    const float* bk = (const float*)d_in[4];
    const float* Wo = (const float*)d_in[5];
    const float* bo = (const float*)d_in[6];
    float* out = (float*)d_out;

    char* ws = (char*)d_ws;
    f16*   Qh     = (f16*)(ws);                                  // 4 MB
    char*  Ksw    = (char*)(ws + (4 << 20));                     // 4 MB (swizzled f16)
    float* rowmax = (float*)(ws + (8 << 20));                    // 256 KB
    float* kmean  = (float*)(ws + (8 << 20) + (256 << 10));      // 8 KB
    float* xmean  = (float*)(ws + (8 << 20) + (264 << 10));      // 8 KB
    float* logits = (float*)(ws + (8 << 20) + (272 << 10));      // 32 KB
    float* wgt    = (float*)(ws + (8 << 20) + (304 << 10));      // 32 KB

    xmean_kernel  <<<dim3(256),  256, 0, stream>>>(x, xmean);
    kmeanW_kernel <<<dim3(8),    256, 0, stream>>>(Wk, bk, xmean, kmean);
    pgemmQK_kernel<<<dim3(256),  512, 0, stream>>>(x, Wq, Wk, bq, bk, Qh, Ksw);
    score_kernel  <<<dim3(512),  256, 0, stream>>>(Qh, Ksw, rowmax);
    logits_kernel <<<dim3(32),   256, 0, stream>>>(Qh, kmean, rowmax, logits);
    softmax_kernel<<<dim3(8),    256, 0, stream>>>(logits, wgt);
    pgemmY_kernel <<<dim3(256),  512, 0, stream>>>(x, Wo, bo, wgt, out);
}

// Round 6
// 102.520 us; speedup vs baseline: 2.7294x; 1.0019x over previous
//
#include <hip/hip_runtime.h>

#define BATCH 8
#define CH 256
#define HWSZ 1024
#define BHW 8192

typedef _Float16 f16;
typedef _Float16 f16x4 __attribute__((ext_vector_type(4)));
typedef _Float16 f16x8 __attribute__((ext_vector_type(8)));
typedef float f32x4 __attribute__((ext_vector_type(4)));
typedef unsigned long long u64;
typedef __attribute__((address_space(3))) unsigned int lds_u32;
typedef __attribute__((address_space(1))) const unsigned int glob_u32;

// ---------------- xmean: xmean[b*256+c] = mean over HW of x[b,c,:] ----------------
__global__ __launch_bounds__(256) void xmean_kernel(const float* __restrict__ x,
                                                    float* __restrict__ xmean)
{
    const int row  = blockIdx.x * 8 + (threadIdx.x >> 5);    // [0, 2048)
    const int part = threadIdx.x & 31;
    const float4* p = (const float4*)(x + (size_t)row * HWSZ);
    float s = 0.f;
#pragma unroll
    for (int i = 0; i < 8; ++i) { float4 v = p[i * 32 + part]; s += v.x + v.y + v.z + v.w; }
    s += __shfl_xor(s, 1, 64);
    s += __shfl_xor(s, 2, 64);
    s += __shfl_xor(s, 4, 64);
    s += __shfl_xor(s, 8, 64);
    s += __shfl_xor(s, 16, 64);
    if (part == 0) xmean[row] = s * (1.0f / HWSZ);
}

// ---------------- kmean[b][co] = Wk[co,:] . xmean[b,:] + bk[co]  (exact fp32) ----------------
__global__ __launch_bounds__(256) void kmeanW_kernel(
    const float* __restrict__ Wk, const float* __restrict__ bk,
    const float* __restrict__ xmean, float* __restrict__ kmean)
{
    __shared__ float xm[CH];
    const int b = blockIdx.x;
    const int tid = threadIdx.x;
    xm[tid] = xmean[b * 256 + tid];
    __syncthreads();

    float acc = 0.f;
    const float4* w = (const float4*)(Wk + tid * CH);
    for (int c4 = 0; c4 < 64; ++c4) {
        float4 wv = w[c4];
        acc = fmaf(wv.x, xm[c4 * 4 + 0], acc);
        acc = fmaf(wv.y, xm[c4 * 4 + 1], acc);
        acc = fmaf(wv.z, xm[c4 * 4 + 2], acc);
        acc = fmaf(wv.w, xm[c4 * 4 + 3], acc);
    }
    kmean[b * 256 + tid] = acc + bk[tid];
}

// ---------------- pgemmQK: Q and K projections, one x-tile pass, f16 MFMA split-x ----------------
// 512 threads = 8 waves; wave owns 32 co rows (t=2); 32 px/block; grid 256.
__global__ __launch_bounds__(512, 1) void pgemmQK_kernel(
    const float* __restrict__ x,
    const float* __restrict__ Wq, const float* __restrict__ Wk,
    const float* __restrict__ bq, const float* __restrict__ bk,
    f16* __restrict__ Qh, char* __restrict__ Ksw)
{
    __shared__ __align__(16) char kbuf[32 * 1024];     // x^T split tile (hi|lo per px)
    __shared__ __align__(16) float xt[256][36];        // fp32 staging; reused as epilogue bounce
    f16* tile = (f16*)&xt[0][0];
    char* tileb = (char*)&xt[0][0];

    const int pxg0 = blockIdx.x * 32;
    const int b    = pxg0 >> 10;
    const int hw0  = pxg0 & 1023;
    const int tid  = threadIdx.x;
    const int lane = tid & 63;
    const int wid  = tid >> 6;
    const int m = lane & 15, g = lane >> 4;

    // Phase A: coalesced load of x[b][0..255][hw0..+32)
    {
        const int f4 = tid & 7;
        const int cs = tid >> 3;           // [0,64)
#pragma unroll
        for (int pass = 0; pass < 4; ++pass) {
            const int c = pass * 64 + cs;
            float4 v = *(const float4*)(x + ((size_t)b * CH + c) * HWSZ + hw0 + f4 * 4);
            *(float4*)&xt[c][f4 * 4] = v;
        }
    }
    __syncthreads();

    // Phase B: transpose + hi/lo split into kbuf
    {
        const int px = tid & 31;
        const int q8 = tid >> 5;           // [0,16)
        const int sw = (px & 7) << 4;
#pragma unroll
        for (int r = 0; r < 2; ++r) {
            f16x8 hi, lo;
#pragma unroll
            for (int i = 0; i < 8; ++i) {
                const int c = q8 * 16 + r * 8 + i;
                float v = xt[c][px];
                f16 h = (f16)v;
                hi[i] = h;
                lo[i] = (f16)(v - (float)h);
            }
            const int base = q8 * 32 + r * 16;
            *(f16x8*)(kbuf + px * 1024 + (base ^ sw)) = hi;
            *(f16x8*)(kbuf + px * 1024 + 512 + (base ^ sw)) = lo;
        }
    }

    // Wq A-frags
    f16x8 a[2][8];
#define LOAD_W(Wsel)                                                                     \
    {                                                                                    \
        _Pragma("unroll")                                                                \
        for (int t = 0; t < 2; ++t)                                                      \
            _Pragma("unroll")                                                            \
            for (int kk = 0; kk < 8; ++kk) {                                             \
                const float* wrow = (Wsel) + (size_t)(wid * 32 + t * 16 + m) * CH + kk * 32 + g * 8; \
                float4 w0 = *(const float4*)(wrow);                                      \
                float4 w1 = *(const float4*)(wrow + 4);                                  \
                f16x8 av;                                                                \
                av[0] = (f16)w0.x; av[1] = (f16)w0.y; av[2] = (f16)w0.z; av[3] = (f16)w0.w; \
                av[4] = (f16)w1.x; av[5] = (f16)w1.y; av[6] = (f16)w1.z; av[7] = (f16)w1.w; \
                a[t][kk] = av;                                                           \
            }                                                                            \
    }
    LOAD_W(Wq);
    __syncthreads();   // kbuf ready, xt free

    const int sw0 = (m & 7) << 4;
    const f32x4 vz = {0.f, 0.f, 0.f, 0.f};
    f32x4 acc[2][2];

#define MFMA_PASS()                                                                      \
    {                                                                                    \
        _Pragma("unroll")                                                                \
        for (int t = 0; t < 2; ++t) { acc[t][0] = vz; acc[t][1] = vz; }                  \
        _Pragma("unroll")                                                                \
        for (int ks = 0; ks < 16; ++ks) {                                                \
            const int X = ks * 64 + g * 16;                                              \
            f16x8 b0 = *(const f16x8*)(kbuf + m * 1024 + (X ^ sw0));                     \
            f16x8 b1 = *(const f16x8*)(kbuf + (16 + m) * 1024 + (X ^ sw0));              \
            _Pragma("unroll")                                                            \
            for (int t = 0; t < 2; ++t) {                                                \
                acc[t][0] = __builtin_amdgcn_mfma_f32_16x16x32_f16(a[t][ks & 7], b0, acc[t][0], 0, 0, 0); \
                acc[t][1] = __builtin_amdgcn_mfma_f32_16x16x32_f16(a[t][ks & 7], b1, acc[t][1], 0, 0, 0); \
            }                                                                            \
        }                                                                                \
    }

    // ---- Q pass ----
    MFMA_PASS();

    // Q epilogue: bounce to LDS, coalesced f16x8 stores
#pragma unroll
    for (int t = 0; t < 2; ++t) {
        const int co0 = wid * 32 + t * 16 + 4 * g;
        float4 bv = *(const float4*)(bq + co0);
        float ba[4] = {bv.x, bv.y, bv.z, bv.w};
#pragma unroll
        for (int u = 0; u < 2; ++u) {
            const int px = u * 16 + m;
#pragma unroll
            for (int j = 0; j < 4; ++j)
                tile[(co0 + j) * 32 + (px ^ (j << 3))] = (f16)(acc[t][u][j] + ba[j]);
        }
    }
    __syncthreads();   // tile written
#pragma unroll
    for (int pass = 0; pass < 2; ++pass) {
        const int co  = pass * 128 + (tid >> 2);
        const int run = tid & 3;
        f16x8 v = *(const f16x8*)(tile + co * 32 + ((run * 8) ^ ((co & 3) << 3)));
        *(f16x8*)(Qh + ((size_t)b * CH + co) * HWSZ + hw0 + run * 8) = v;
    }

    // ---- K pass ----
    LOAD_W(Wk);
    MFMA_PASS();
    __syncthreads();   // Q tile reads complete before K overwrites

#pragma unroll
    for (int t = 0; t < 2; ++t) {
        const int co0 = wid * 32 + t * 16 + 4 * g;
        float4 bv = *(const float4*)(bk + co0);
        float ba[4] = {bv.x, bv.y, bv.z, bv.w};
#pragma unroll
        for (int u = 0; u < 2; ++u) {
            const int px = u * 16 + m;
            f16x4 pk;
#pragma unroll
            for (int j = 0; j < 4; ++j) pk[j] = (f16)(acc[t][u][j] + ba[j]);
            *(f16x4*)(tileb + px * 512 + ((co0 * 2) ^ (m << 3))) = pk;
        }
    }
    __syncthreads();
    {
        const int px = tid & 31;
        const int rp = tid >> 5;           // [0,16)
        const int kloc = (px & 15) << 3;
        const int kglb = (px & 7) << 4;
        char* grow = Ksw + (size_t)(pxg0 + px) * 512;
#pragma unroll
        for (int i = 0; i < 2; ++i) {
            const int r = rp + i * 16;
            u64 a0 = *(const u64*)(tileb + px * 512 + ((r * 16) ^ kloc));
            u64 a1 = *(const u64*)(tileb + px * 512 + ((r * 16 + 8) ^ kloc));
            char* gdst = grow + ((r * 16) ^ kglb);
            *(u64*)gdst = a0;
            *(u64*)(gdst + 8) = a1;
        }
    }
#undef MFMA_PASS
#undef LOAD_W
}

// ---------------- score: 128 rows x 1024 cols per 256-thread block, t=4, 2 blocks/CU ----------------
// K-loop uses counted vmcnt (T4): prefetch loads stay in flight across barriers; never vmcnt(0)
// in the main loop. STAGE issues exactly 8 global_load_lds, so vmcnt(8) after issuing chunk k+1
// guarantees chunk k has landed (vmcnt decrements in issue order).
__global__ __launch_bounds__(256, 2) void score_kernel(
    const f16* __restrict__ Qh, const char* __restrict__ Ksw, float* __restrict__ rowmax)
{
    __shared__ __align__(16) char kbuf[2][32768];   // 64 cols x 512B, double buffered
    __shared__ float lds_rm[128][2];

    const int batch = blockIdx.x & 7;
    const int r0    = (blockIdx.x >> 3) * 128;
    const int tid   = threadIdx.x;
    const int lane  = tid & 63;
    const int wid   = tid >> 6;          // 4 waves
    const int wr = wid >> 1, wc = wid & 1;
    const int m = lane & 15, g = lane >> 4;
    const int rbase = r0 + wr * 64;

    const char* kbase = Ksw + (size_t)batch * HWSZ * 512;

#define STAGE(buf, ch)                                                                   \
    {                                                                                    \
        const char* _src = kbase + (ch) * 64 * 512 + tid * 16;                           \
        char* _dst = &kbuf[buf][tid * 16];                                               \
        _Pragma("unroll")                                                                \
        for (int k = 0; k < 8; ++k)                                                      \
            __builtin_amdgcn_global_load_lds((glob_u32*)(_src + k * 4096),               \
                                             (lds_u32*)(_dst + k * 4096), 16, 0, 0);     \
    }

    STAGE(0, 0);

    // A fragments: 64 rows x K=256 in registers (128 VGPR)
    f16x8 a[4][8];
#pragma unroll
    for (int t = 0; t < 4; ++t)
#pragma unroll
        for (int kk = 0; kk < 8; ++kk)
            a[t][kk] = *(const f16x8*)(Qh + (size_t)(rbase + t * 16 + m) * CH + kk * 32 + 8 * g);

    int boff[8][2];
    {
        const int sw = (m & 7) << 4;
#pragma unroll
        for (int kk = 0; kk < 8; ++kk)
#pragma unroll
            for (int u2 = 0; u2 < 2; ++u2) {
                const int col = wc * 32 + u2 * 16 + m;
                boff[kk][u2] = col * 512 + ((kk * 64 + g * 16) ^ sw);
            }
    }

    float rm[4][4];
#pragma unroll
    for (int t = 0; t < 4; ++t)
#pragma unroll
        for (int jj = 0; jj < 4; ++jj) rm[t][jj] = -1e30f;

    int cur = 0;
    for (int ch = 0; ch < 16; ++ch) {
        if (ch < 15) {
            STAGE(cur ^ 1, ch + 1);
            // wait for chunk ch (8 loads of chunk ch+1 remain in flight across the barrier)
            asm volatile("s_waitcnt vmcnt(8)" ::: "memory");
        } else {
            asm volatile("s_waitcnt vmcnt(0)" ::: "memory");
        }
        __builtin_amdgcn_s_barrier();   // all waves' chunk-ch loads landed; prev reads done

        const char* kb = &kbuf[cur][0];
        f32x4 acc[4][2];
        const f32x4 vz = {0.f, 0.f, 0.f, 0.f};
#pragma unroll
        for (int t = 0; t < 4; ++t) { acc[t][0] = vz; acc[t][1] = vz; }

#pragma unroll
        for (int kk = 0; kk < 8; ++kk) {
            f16x8 bfr[2];
            bfr[0] = *(const f16x8*)(kb + boff[kk][0]);
            bfr[1] = *(const f16x8*)(kb + boff[kk][1]);
#pragma unroll
            for (int t = 0; t < 4; ++t) {
                acc[t][0] = __builtin_amdgcn_mfma_f32_16x16x32_f16(a[t][kk], bfr[0], acc[t][0], 0, 0, 0);
                acc[t][1] = __builtin_amdgcn_mfma_f32_16x16x32_f16(a[t][kk], bfr[1], acc[t][1], 0, 0, 0);
            }
        }

#pragma unroll
        for (int t = 0; t < 4; ++t)
#pragma unroll
            for (int jj = 0; jj < 4; ++jj)
                rm[t][jj] = fmaxf(rm[t][jj], fmaxf(acc[t][0][jj], acc[t][1][jj]));

        asm volatile("" ::: "memory");   // pin ds_reads before the reuse barrier
        __builtin_amdgcn_s_barrier();    // reads of buf[cur] complete before next STAGE overwrites
        cur ^= 1;
    }
#undef STAGE

#pragma unroll
    for (int d = 1; d < 16; d <<= 1)
#pragma unroll
        for (int t = 0; t < 4; ++t)
#pragma unroll
            for (int jj = 0; jj < 4; ++jj)
                rm[t][jj] = fmaxf(rm[t][jj], __shfl_xor(rm[t][jj], d, 64));

    if (m == 0) {
#pragma unroll
        for (int t = 0; t < 4; ++t)
#pragma unroll
            for (int jj = 0; jj < 4; ++jj)
                lds_rm[wr * 64 + t * 16 + g * 4 + jj][wc] = rm[t][jj];
    }
    __syncthreads();
    if (tid < 128)
        rowmax[(size_t)(r0 + tid) * BATCH + batch] = fmaxf(lds_rm[tid][0], lds_rm[tid][1]);
}

// ---------------- logits ----------------
__global__ __launch_bounds__(256) void logits_kernel(
    const f16* __restrict__ Qh, const float* __restrict__ kmean,
    const float* __restrict__ rowmax, float* __restrict__ logits)
{
    __shared__ float km[BATCH][CH];
    const int tid = threadIdx.x;
#pragma unroll
    for (int i = 0; i < 8; ++i) km[i][tid] = kmean[i * 256 + tid];
    __syncthreads();

    const int r = blockIdx.x * 256 + tid;
    float acc[8];
#pragma unroll
    for (int b = 0; b < 8; ++b) acc[b] = 0.f;

    const f16x8* q = (const f16x8*)(Qh + (size_t)r * CH);
    for (int c8 = 0; c8 < 32; ++c8) {
        f16x8 qv = q[c8];
        float qf[8];
#pragma unroll
        for (int i = 0; i < 8; ++i) qf[i] = (float)qv[i];
#pragma unroll
        for (int b = 0; b < 8; ++b) {
            float4 k0 = *(const float4*)&km[b][c8 * 8];
            float4 k1 = *(const float4*)&km[b][c8 * 8 + 4];
            acc[b] = fmaf(qf[0], k0.x, acc[b]); acc[b] = fmaf(qf[1], k0.y, acc[b]);
            acc[b] = fmaf(qf[2], k0.z, acc[b]); acc[b] = fmaf(qf[3], k0.w, acc[b]);
            acc[b] = fmaf(qf[4], k1.x, acc[b]); acc[b] = fmaf(qf[5], k1.y, acc[b]);
            acc[b] = fmaf(qf[6], k1.z, acc[b]); acc[b] = fmaf(qf[7], k1.w, acc[b]);
        }
    }
    float lg = 0.f;
#pragma unroll
    for (int b = 0; b < 8; ++b) lg += rowmax[(size_t)r * 8 + b] + acc[b];
    logits[r] = lg * (1.0f / 128.0f);
}

// ---------------- softmax over HW per batch ----------------
__global__ __launch_bounds__(256) void softmax_kernel(const float* __restrict__ logits,
                                                      float* __restrict__ wgt)
{
    const int br = blockIdx.x, tid = threadIdx.x;
    __shared__ float red[256];
    float l[4];
#pragma unroll
    for (int i = 0; i < 4; ++i) l[i] = logits[br * HWSZ + i * 256 + tid];

    float mx = fmaxf(fmaxf(l[0], l[1]), fmaxf(l[2], l[3]));
    red[tid] = mx;
    __syncthreads();
    for (int s = 128; s > 0; s >>= 1) {
        if (tid < s) red[tid] = fmaxf(red[tid], red[tid + s]);
        __syncthreads();
    }
    mx = red[0];
    __syncthreads();

    float e[4], sm = 0.f;
#pragma unroll
    for (int i = 0; i < 4; ++i) { e[i] = expf(l[i] - mx); sm += e[i]; }
    red[tid] = sm;
    __syncthreads();
    for (int s = 128; s > 0; s >>= 1) {
        if (tid < s) red[tid] += red[tid + s];
        __syncthreads();
    }
    const float inv = 1.0f / red[0];
#pragma unroll
    for (int i = 0; i < 4; ++i)
        wgt[br * HWSZ + i * 256 + tid] = e[i] * inv;
}

// ---------------- pgemmY: out = wgt * (Wo @ x) + bo, hi-only f16 MFMA, gate fused ----------------
__global__ __launch_bounds__(512, 1) void pgemmY_kernel(
    const float* __restrict__ x, const float* __restrict__ Wo, const float* __restrict__ bo,
    const float* __restrict__ wgt, float* __restrict__ out)
{
    __shared__ __align__(16) char kbuf[16 * 1024];     // hi-only x^T tile
    __shared__ __align__(16) float xt[256][36];

    const int pxg0 = blockIdx.x * 32;
    const int b    = pxg0 >> 10;
    const int hw0  = pxg0 & 1023;
    const int tid  = threadIdx.x;
    const int lane = tid & 63;
    const int wid  = tid >> 6;
    const int m = lane & 15, g = lane >> 4;

    {
        const int f4 = tid & 7;
        const int cs = tid >> 3;
#pragma unroll
        for (int pass = 0; pass < 4; ++pass) {
            const int c = pass * 64 + cs;
            float4 v = *(const float4*)(x + ((size_t)b * CH + c) * HWSZ + hw0 + f4 * 4);
            *(float4*)&xt[c][f4 * 4] = v;
        }
    }
    __syncthreads();

    {
        const int px = tid & 31;
        const int q8 = tid >> 5;
        const int sw = (px & 7) << 4;
#pragma unroll
        for (int r = 0; r < 2; ++r) {
            f16x8 hi;
#pragma unroll
            for (int i = 0; i < 8; ++i)
                hi[i] = (f16)xt[q8 * 16 + r * 8 + i][px];
            *(f16x8*)(kbuf + px * 512 + ((q8 * 32 + r * 16) ^ sw)) = hi;
        }
    }

    f16x8 a[2][8];
#pragma unroll
    for (int t = 0; t < 2; ++t)
#pragma unroll
        for (int kk = 0; kk < 8; ++kk) {
            const float* wrow = Wo + (size_t)(wid * 32 + t * 16 + m) * CH + kk * 32 + g * 8;
            float4 w0 = *(const float4*)(wrow);
            float4 w1 = *(const float4*)(wrow + 4);
            f16x8 av;
            av[0] = (f16)w0.x; av[1] = (f16)w0.y; av[2] = (f16)w0.z; av[3] = (f16)w0.w;
            av[4] = (f16)w1.x; av[5] = (f16)w1.y; av[6] = (f16)w1.z; av[7] = (f16)w1.w;
            a[t][kk] = av;
        }

    __syncthreads();

    f32x4 acc[2][2];
    const f32x4 vz = {0.f, 0.f, 0.f, 0.f};
#pragma unroll
    for (int t = 0; t < 2; ++t) { acc[t][0] = vz; acc[t][1] = vz; }

    const int sw0 = (m & 7) << 4;
#pragma unroll
    for (int ks = 0; ks < 8; ++ks) {
        const int X = ks * 64 + g * 16;
        f16x8 b0 = *(const f16x8*)(kbuf + m * 512 + (X ^ sw0));
        f16x8 b1 = *(const f16x8*)(kbuf + (16 + m) * 512 + (X ^ sw0));
#pragma unroll
        for (int t = 0; t < 2; ++t) {
            acc[t][0] = __builtin_amdgcn_mfma_f32_16x16x32_f16(a[t][ks], b0, acc[t][0], 0, 0, 0);
            acc[t][1] = __builtin_amdgcn_mfma_f32_16x16x32_f16(a[t][ks], b1, acc[t][1], 0, 0, 0);
        }
    }

    // epilogue: gate + bias, direct fp32 stores
    float wv[2];
    wv[0] = wgt[b * HWSZ + hw0 + m];
    wv[1] = wgt[b * HWSZ + hw0 + 16 + m];
#pragma unroll
    for (int t = 0; t < 2; ++t) {
        const int co0 = wid * 32 + t * 16 + 4 * g;
        float4 bv = *(const float4*)(bo + co0);
        float ba[4] = {bv.x, bv.y, bv.z, bv.w};
#pragma unroll
        for (int u = 0; u < 2; ++u)
#pragma unroll
            for (int j = 0; j < 4; ++j)
                out[((size_t)b * CH + co0 + j) * HWSZ + hw0 + u * 16 + m] =
                    fmaf(acc[t][u][j], wv[u], ba[j]);
    }
}

extern "C" void kernel_launch(void* const* d_in, const int* in_sizes, int n_in,
                              void* d_out, int out_size, void* d_ws, size_t ws_size,
                              hipStream_t stream)
{
    const float* x  = (const float*)d_in[0];
    const float* Wq = (const float*)d_in[1];
    const float* bq = (const float*)d_in[2];
    const float* Wk = (const float*)d_in[3];
    const float* bk = (const float*)d_in[4];
    const float* Wo = (const float*)d_in[5];
    const float* bo = (const float*)d_in[6];
    float* out = (float*)d_out;

    char* ws = (char*)d_ws;
    f16*   Qh     = (f16*)(ws);                                  // 4 MB
    char*  Ksw    = (char*)(ws + (4 << 20));                     // 4 MB (swizzled f16)
    float* rowmax = (float*)(ws + (8 << 20));                    // 256 KB
    float* kmean  = (float*)(ws + (8 << 20) + (256 << 10));      // 8 KB
    float* xmean  = (float*)(ws + (8 << 20) + (264 << 10));      // 8 KB
    float* logits = (float*)(ws + (8 << 20) + (272 << 10));      // 32 KB
    float* wgt    = (float*)(ws + (8 << 20) + (304 << 10));      // 32 KB

    xmean_kernel  <<<dim3(256),  256, 0, stream>>>(x, xmean);
    kmeanW_kernel <<<dim3(8),    256, 0, stream>>>(Wk, bk, xmean, kmean);
    pgemmQK_kernel<<<dim3(256),  512, 0, stream>>>(x, Wq, Wk, bq, bk, Qh, Ksw);
    score_kernel  <<<dim3(512),  256, 0, stream>>>(Qh, Ksw, rowmax);
    logits_kernel <<<dim3(32),   256, 0, stream>>>(Qh, kmean, rowmax, logits);
    softmax_kernel<<<dim3(8),    256, 0, stream>>>(logits, wgt);
    pgemmY_kernel <<<dim3(256),  512, 0, stream>>>(x, Wo, bo, wgt, out);
}

// Round 8
// 91.345 us; speedup vs baseline: 3.0633x; 1.1223x over previous
//
#include <hip/hip_runtime.h>

#define BATCH 8
#define CH 256
#define HWSZ 1024
#define BHW 8192

typedef _Float16 f16;
typedef _Float16 f16x4 __attribute__((ext_vector_type(4)));
typedef _Float16 f16x8 __attribute__((ext_vector_type(8)));
typedef float f32x4 __attribute__((ext_vector_type(4)));
typedef unsigned long long u64;
typedef __attribute__((address_space(3))) unsigned int lds_u32;
typedef __attribute__((address_space(1))) const unsigned int glob_u32;

// ---------------- kmean[b][co] = Wk[co,:] . (xsum[b,:]/HW) + bk[co] ----------------
__global__ __launch_bounds__(256) void kmeanW_kernel(
    const float* __restrict__ Wk, const float* __restrict__ bk,
    const float* __restrict__ xsum, float* __restrict__ kmean)
{
    __shared__ float xm[CH];
    const int b = blockIdx.x;
    const int tid = threadIdx.x;
    xm[tid] = xsum[b * 256 + tid] * (1.0f / HWSZ);
    __syncthreads();

    float acc = 0.f;
    const float4* w = (const float4*)(Wk + tid * CH);
    for (int c4 = 0; c4 < 64; ++c4) {
        float4 wv = w[c4];
        acc = fmaf(wv.x, xm[c4 * 4 + 0], acc);
        acc = fmaf(wv.y, xm[c4 * 4 + 1], acc);
        acc = fmaf(wv.z, xm[c4 * 4 + 2], acc);
        acc = fmaf(wv.w, xm[c4 * 4 + 3], acc);
    }
    kmean[b * 256 + tid] = acc + bk[tid];
}

// ---------------- pgemmQKY: Q, K, Y projections from ONE x-tile pass + xsum atomics ----------------
// 512 threads = 8 waves; wave owns 32 co rows (t=2); 32 px/block; grid 256.
// Q/K use split-x (K=512, fp32-class accuracy); Y (pre-gate) uses hi-only (gate attenuates err).
__global__ __launch_bounds__(512, 1) void pgemmQKY_kernel(
    const float* __restrict__ x,
    const float* __restrict__ Wq, const float* __restrict__ Wk, const float* __restrict__ Wo,
    const float* __restrict__ bq, const float* __restrict__ bk,
    f16* __restrict__ Qh, char* __restrict__ Ksw, f16* __restrict__ Yh,
    float* __restrict__ xsum)
{
    __shared__ __align__(16) char kbuf[32 * 1024];     // x^T split tile (hi|lo per px)
    __shared__ __align__(16) float xt[256][36];        // fp32 staging; reused as epilogue bounce
    f16* tile = (f16*)&xt[0][0];
    char* tileb = (char*)&xt[0][0];

    const int pxg0 = blockIdx.x * 32;
    const int b    = pxg0 >> 10;
    const int hw0  = pxg0 & 1023;
    const int tid  = threadIdx.x;
    const int lane = tid & 63;
    const int wid  = tid >> 6;
    const int m = lane & 15, g = lane >> 4;

    // Phase A: coalesced load of x[b][0..255][hw0..+32)
    {
        const int f4 = tid & 7;
        const int cs = tid >> 3;           // [0,64)
#pragma unroll
        for (int pass = 0; pass < 4; ++pass) {
            const int c = pass * 64 + cs;
            float4 v = *(const float4*)(x + ((size_t)b * CH + c) * HWSZ + hw0 + f4 * 4);
            *(float4*)&xt[c][f4 * 4] = v;
        }
    }
    __syncthreads();

    // Phase B: transpose + hi/lo split into kbuf
    {
        const int px = tid & 31;
        const int q8 = tid >> 5;           // [0,16)
        const int sw = (px & 7) << 4;
#pragma unroll
        for (int r = 0; r < 2; ++r) {
            f16x8 hi, lo;
#pragma unroll
            for (int i = 0; i < 8; ++i) {
                const int c = q8 * 16 + r * 8 + i;
                float v = xt[c][px];
                f16 h = (f16)v;
                hi[i] = h;
                lo[i] = (f16)(v - (float)h);
            }
            const int base = q8 * 32 + r * 16;
            *(f16x8*)(kbuf + px * 1024 + (base ^ sw)) = hi;
            *(f16x8*)(kbuf + px * 1024 + 512 + (base ^ sw)) = lo;
        }
    }

    // xsum partials (reads xt; completes before the barrier below)
    if (tid < 256) {
        float s = 0.f;
#pragma unroll
        for (int i4 = 0; i4 < 8; ++i4) {
            float4 v = *(const float4*)&xt[tid][i4 * 4];
            s += v.x + v.y + v.z + v.w;
        }
        atomicAdd(&xsum[b * 256 + tid], s);
    }

    f16x8 aA[2][8], aB[2][8];
#define LOAD_W(dst, Wsel)                                                                \
    {                                                                                    \
        _Pragma("unroll")                                                                \
        for (int t = 0; t < 2; ++t)                                                      \
            _Pragma("unroll")                                                            \
            for (int kk = 0; kk < 8; ++kk) {                                             \
                const float* wrow = (Wsel) + (size_t)(wid * 32 + t * 16 + m) * CH + kk * 32 + g * 8; \
                float4 w0 = *(const float4*)(wrow);                                      \
                float4 w1 = *(const float4*)(wrow + 4);                                  \
                f16x8 av;                                                                \
                av[0] = (f16)w0.x; av[1] = (f16)w0.y; av[2] = (f16)w0.z; av[3] = (f16)w0.w; \
                av[4] = (f16)w1.x; av[5] = (f16)w1.y; av[6] = (f16)w1.z; av[7] = (f16)w1.w; \
                dst[t][kk] = av;                                                         \
            }                                                                            \
    }
    LOAD_W(aA, Wq);
    __syncthreads();   // kbuf ready; all xt reads (B + xsum) done

    const int sw0 = (m & 7) << 4;
    const f32x4 vz = {0.f, 0.f, 0.f, 0.f};
    f32x4 acc[2][2];

#define MFMA_PASS(ARR, NKS)                                                              \
    {                                                                                    \
        _Pragma("unroll")                                                                \
        for (int t = 0; t < 2; ++t) { acc[t][0] = vz; acc[t][1] = vz; }                  \
        _Pragma("unroll")                                                                \
        for (int ks = 0; ks < (NKS); ++ks) {                                             \
            const int X = ks * 64 + g * 16;                                              \
            f16x8 b0 = *(const f16x8*)(kbuf + m * 1024 + (X ^ sw0));                     \
            f16x8 b1 = *(const f16x8*)(kbuf + (16 + m) * 1024 + (X ^ sw0));              \
            _Pragma("unroll")                                                            \
            for (int t = 0; t < 2; ++t) {                                                \
                acc[t][0] = __builtin_amdgcn_mfma_f32_16x16x32_f16(ARR[t][ks & 7], b0, acc[t][0], 0, 0, 0); \
                acc[t][1] = __builtin_amdgcn_mfma_f32_16x16x32_f16(ARR[t][ks & 7], b1, acc[t][1], 0, 0, 0); \
            }                                                                            \
        }                                                                                \
    }

    // ---- Q pass (K=512 split) ----
    MFMA_PASS(aA, 16);
    LOAD_W(aB, Wk);   // prefetch K weights under Q epilogue

    // Q epilogue: bounce to LDS, coalesced f16x8 stores
#pragma unroll
    for (int t = 0; t < 2; ++t) {
        const int co0 = wid * 32 + t * 16 + 4 * g;
        float4 bv = *(const float4*)(bq + co0);
        float ba[4] = {bv.x, bv.y, bv.z, bv.w};
#pragma unroll
        for (int u = 0; u < 2; ++u) {
            const int px = u * 16 + m;
#pragma unroll
            for (int j = 0; j < 4; ++j)
                tile[(co0 + j) * 32 + (px ^ (j << 3))] = (f16)(acc[t][u][j] + ba[j]);
        }
    }
    __syncthreads();   // tile written
#pragma unroll
    for (int pass = 0; pass < 2; ++pass) {
        const int co  = pass * 128 + (tid >> 2);
        const int run = tid & 3;
        f16x8 v = *(const f16x8*)(tile + co * 32 + ((run * 8) ^ ((co & 3) << 3)));
        *(f16x8*)(Qh + ((size_t)b * CH + co) * HWSZ + hw0 + run * 8) = v;
    }

    // ---- K pass (K=512 split) ----
    MFMA_PASS(aB, 16);
    LOAD_W(aA, Wo);   // prefetch Y weights (aA free after Q pass)
    __syncthreads();   // Q tile reads complete before K bounce overwrites

#pragma unroll
    for (int t = 0; t < 2; ++t) {
        const int co0 = wid * 32 + t * 16 + 4 * g;
        float4 bv = *(const float4*)(bk + co0);
        float ba[4] = {bv.x, bv.y, bv.z, bv.w};
#pragma unroll
        for (int u = 0; u < 2; ++u) {
            const int px = u * 16 + m;
            f16x4 pk;
#pragma unroll
            for (int j = 0; j < 4; ++j) pk[j] = (f16)(acc[t][u][j] + ba[j]);
            *(f16x4*)(tileb + px * 512 + ((co0 * 2) ^ (m << 3))) = pk;
        }
    }
    __syncthreads();
    {
        const int px = tid & 31;
        const int rp = tid >> 5;           // [0,16)
        const int kloc = (px & 15) << 3;
        const int kglb = (px & 7) << 4;
        char* grow = Ksw + (size_t)(pxg0 + px) * 512;
#pragma unroll
        for (int i = 0; i < 2; ++i) {
            const int r = rp + i * 16;
            u64 a0 = *(const u64*)(tileb + px * 512 + ((r * 16) ^ kloc));
            u64 a1 = *(const u64*)(tileb + px * 512 + ((r * 16 + 8) ^ kloc));
            char* gdst = grow + ((r * 16) ^ kglb);
            *(u64*)gdst = a0;
            *(u64*)(gdst + 8) = a1;
        }
    }

    // ---- Y pass (hi-only, K=256; pre-gate, no bias) ----
    MFMA_PASS(aA, 8);
    __syncthreads();   // K tileb reads complete before Y bounce overwrites

#pragma unroll
    for (int t = 0; t < 2; ++t) {
        const int co0 = wid * 32 + t * 16 + 4 * g;
#pragma unroll
        for (int u = 0; u < 2; ++u) {
            const int px = u * 16 + m;
#pragma unroll
            for (int j = 0; j < 4; ++j)
                tile[(co0 + j) * 32 + (px ^ (j << 3))] = (f16)acc[t][u][j];
        }
    }
    __syncthreads();
#pragma unroll
    for (int pass = 0; pass < 2; ++pass) {
        const int co  = pass * 128 + (tid >> 2);
        const int run = tid & 3;
        f16x8 v = *(const f16x8*)(tile + co * 32 + ((run * 8) ^ ((co & 3) << 3)));
        *(f16x8*)(Yh + ((size_t)b * CH + co) * HWSZ + hw0 + run * 8) = v;
    }
#undef MFMA_PASS
#undef LOAD_W
}

// ---------------- score: 128 rows x 1024 cols/block + fused logits atomics ----------------
// grid 512: batch = bid&7 (XCD-affine), rowblock = bid>>3. Counted vmcnt (T4) in K-loop.
// logits[r] += (rowmax(r,batch) + q_r . kmean[batch]) / 128   (one add per batch per row)
__global__ __launch_bounds__(256, 2) void score_kernel(
    const f16* __restrict__ Qh, const char* __restrict__ Ksw,
    const float* __restrict__ kmean, float* __restrict__ logits)
{
    __shared__ __align__(16) char kbuf[2][32768];   // 64 cols x 512B, double buffered
    __shared__ float lds_rm[128][2];
    __shared__ float lds_dq[128];
    __shared__ float km[CH];

    const int batch = blockIdx.x & 7;
    const int r0    = (blockIdx.x >> 3) * 128;
    const int tid   = threadIdx.x;
    const int lane  = tid & 63;
    const int wid   = tid >> 6;          // 4 waves
    const int wr = wid >> 1, wc = wid & 1;
    const int m = lane & 15, g = lane >> 4;
    const int rbase = r0 + wr * 64;

    km[tid] = kmean[batch * 256 + tid];

    const char* kbase = Ksw + (size_t)batch * HWSZ * 512;

#define STAGE(buf, ch)                                                                   \
    {                                                                                    \
        const char* _src = kbase + (ch) * 64 * 512 + tid * 16;                           \
        char* _dst = &kbuf[buf][tid * 16];                                               \
        _Pragma("unroll")                                                                \
        for (int k = 0; k < 8; ++k)                                                      \
            __builtin_amdgcn_global_load_lds((glob_u32*)(_src + k * 4096),               \
                                             (lds_u32*)(_dst + k * 4096), 16, 0, 0);     \
    }

    STAGE(0, 0);

    // A fragments: 64 rows x K=256 in registers
    f16x8 a[4][8];
#pragma unroll
    for (int t = 0; t < 4; ++t)
#pragma unroll
        for (int kk = 0; kk < 8; ++kk)
            a[t][kk] = *(const f16x8*)(Qh + (size_t)(rbase + t * 16 + m) * CH + kk * 32 + 8 * g);

    int boff[8][2];
    {
        const int sw = (m & 7) << 4;
#pragma unroll
        for (int kk = 0; kk < 8; ++kk)
#pragma unroll
            for (int u2 = 0; u2 < 2; ++u2) {
                const int col = wc * 32 + u2 * 16 + m;
                boff[kk][u2] = col * 512 + ((kk * 64 + g * 16) ^ sw);
            }
    }

    float rm[4][4];
#pragma unroll
    for (int t = 0; t < 4; ++t)
#pragma unroll
        for (int jj = 0; jj < 4; ++jj) rm[t][jj] = -1e30f;

    int cur = 0;
    for (int ch = 0; ch < 16; ++ch) {
        if (ch < 15) {
            STAGE(cur ^ 1, ch + 1);
            asm volatile("s_waitcnt vmcnt(8)" ::: "memory");
        } else {
            asm volatile("s_waitcnt vmcnt(0)" ::: "memory");
        }
        __builtin_amdgcn_s_barrier();

        const char* kb = &kbuf[cur][0];
        f32x4 acc[4][2];
        const f32x4 vz = {0.f, 0.f, 0.f, 0.f};
#pragma unroll
        for (int t = 0; t < 4; ++t) { acc[t][0] = vz; acc[t][1] = vz; }

#pragma unroll
        for (int kk = 0; kk < 8; ++kk) {
            f16x8 bfr[2];
            bfr[0] = *(const f16x8*)(kb + boff[kk][0]);
            bfr[1] = *(const f16x8*)(kb + boff[kk][1]);
#pragma unroll
            for (int t = 0; t < 4; ++t) {
                acc[t][0] = __builtin_amdgcn_mfma_f32_16x16x32_f16(a[t][kk], bfr[0], acc[t][0], 0, 0, 0);
                acc[t][1] = __builtin_amdgcn_mfma_f32_16x16x32_f16(a[t][kk], bfr[1], acc[t][1], 0, 0, 0);
            }
        }

#pragma unroll
        for (int t = 0; t < 4; ++t)
#pragma unroll
            for (int jj = 0; jj < 4; ++jj)
                rm[t][jj] = fmaxf(rm[t][jj], fmaxf(acc[t][0][jj], acc[t][1][jj]));

        asm volatile("" ::: "memory");
        __builtin_amdgcn_s_barrier();
        cur ^= 1;
    }
#undef STAGE

    // reduce max over the 16 column lanes
#pragma unroll
    for (int d = 1; d < 16; d <<= 1)
#pragma unroll
        for (int t = 0; t < 4; ++t)
#pragma unroll
            for (int jj = 0; jj < 4; ++jj)
                rm[t][jj] = fmaxf(rm[t][jj], __shfl_xor(rm[t][jj], d, 64));

    // q . kmean[batch] per lane-row (rbase + t*16 + m), reduced over g
    float dq[4];
#pragma unroll
    for (int t = 0; t < 4; ++t) {
        float s = 0.f;
#pragma unroll
        for (int kk = 0; kk < 8; ++kk)
#pragma unroll
            for (int i = 0; i < 8; ++i)
                s = fmaf((float)a[t][kk][i], km[kk * 32 + 8 * g + i], s);
        s += __shfl_xor(s, 16, 64);
        s += __shfl_xor(s, 32, 64);
        dq[t] = s;
    }

    if (m == 0) {
#pragma unroll
        for (int t = 0; t < 4; ++t)
#pragma unroll
            for (int jj = 0; jj < 4; ++jj)
                lds_rm[wr * 64 + t * 16 + g * 4 + jj][wc] = rm[t][jj];
    }
    if (wc == 0 && lane < 16) {
#pragma unroll
        for (int t = 0; t < 4; ++t)
            lds_dq[wr * 64 + t * 16 + lane] = dq[t];
    }
    __syncthreads();
    if (tid < 128) {
        float v = fmaxf(lds_rm[tid][0], lds_rm[tid][1]) + lds_dq[tid];
        atomicAdd(logits + r0 + tid, v * (1.0f / 128.0f));
    }
}

// ---------------- softmax over HW per batch ----------------
__global__ __launch_bounds__(256) void softmax_kernel(const float* __restrict__ logits,
                                                      float* __restrict__ wgt)
{
    const int br = blockIdx.x, tid = threadIdx.x;
    __shared__ float red[256];
    float l[4];
#pragma unroll
    for (int i = 0; i < 4; ++i) l[i] = logits[br * HWSZ + i * 256 + tid];

    float mx = fmaxf(fmaxf(l[0], l[1]), fmaxf(l[2], l[3]));
    red[tid] = mx;
    __syncthreads();
    for (int s = 128; s > 0; s >>= 1) {
        if (tid < s) red[tid] = fmaxf(red[tid], red[tid + s]);
        __syncthreads();
    }
    mx = red[0];
    __syncthreads();

    float e[4], sm = 0.f;
#pragma unroll
    for (int i = 0; i < 4; ++i) { e[i] = expf(l[i] - mx); sm += e[i]; }
    red[tid] = sm;
    __syncthreads();
    for (int s = 128; s > 0; s >>= 1) {
        if (tid < s) red[tid] += red[tid + s];
        __syncthreads();
    }
    const float inv = 1.0f / red[0];
#pragma unroll
    for (int i = 0; i < 4; ++i)
        wgt[br * HWSZ + i * 256 + tid] = e[i] * inv;
}

// ---------------- gateY: out = wgt * Y + bo ----------------
// 2,097,152 elements / (256 threads * 8 per thread) = 1024 blocks (NOT 4096 — r7 OOB bug)
__global__ __launch_bounds__(256) void gateY_kernel(const f16* __restrict__ Yh,
                                                    const float* __restrict__ wgt,
                                                    const float* __restrict__ bo,
                                                    float* __restrict__ out)
{
    const size_t idx = ((size_t)blockIdx.x * 256 + threadIdx.x) * 8;
    const int b  = (int)(idx >> 18);
    const int c  = (int)(idx >> 10) & 255;
    const int hw = (int)idx & 1023;

    f16x8 y = *(const f16x8*)(Yh + idx);
    float4 w0 = *(const float4*)(wgt + b * HWSZ + hw);
    float4 w1 = *(const float4*)(wgt + b * HWSZ + hw + 4);
    const float bov = bo[c];

    float4 o0, o1;
    o0.x = fmaf((float)y[0], w0.x, bov); o0.y = fmaf((float)y[1], w0.y, bov);
    o0.z = fmaf((float)y[2], w0.z, bov); o0.w = fmaf((float)y[3], w0.w, bov);
    o1.x = fmaf((float)y[4], w1.x, bov); o1.y = fmaf((float)y[5], w1.y, bov);
    o1.z = fmaf((float)y[6], w1.z, bov); o1.w = fmaf((float)y[7], w1.w, bov);
    *(float4*)(out + idx)     = o0;
    *(float4*)(out + idx + 4) = o1;
}

extern "C" void kernel_launch(void* const* d_in, const int* in_sizes, int n_in,
                              void* d_out, int out_size, void* d_ws, size_t ws_size,
                              hipStream_t stream)
{
    const float* x  = (const float*)d_in[0];
    const float* Wq = (const float*)d_in[1];
    const float* bq = (const float*)d_in[2];
    const float* Wk = (const float*)d_in[3];
    const float* bk = (const float*)d_in[4];
    const float* Wo = (const float*)d_in[5];
    const float* bo = (const float*)d_in[6];
    float* out = (float*)d_out;

    char* ws = (char*)d_ws;
    f16*   Qh     = (f16*)(ws);                                   // 4 MB
    char*  Ksw    = (char*)(ws + (4 << 20));                      // 4 MB (swizzled f16)
    f16*   Yh     = (f16*)(ws + (8 << 20));                       // 4 MB (pre-gate Y, f16)
    float* xsum   = (float*)(ws + (12 << 20));                    // 8 KB   \ zeroed together
    float* logits = (float*)(ws + (12 << 20) + (8 << 10));        // 32 KB  /
    float* kmean  = (float*)(ws + (12 << 20) + (40 << 10));       // 8 KB
    float* wgt    = (float*)(ws + (12 << 20) + (48 << 10));       // 32 KB

    hipMemsetAsync(xsum, 0, 40 << 10, stream);   // xsum + logits (accumulated via atomics)

    pgemmQKY_kernel<<<dim3(256),  512, 0, stream>>>(x, Wq, Wk, Wo, bq, bk, Qh, Ksw, Yh, xsum);
    kmeanW_kernel  <<<dim3(8),    256, 0, stream>>>(Wk, bk, xsum, kmean);
    score_kernel   <<<dim3(512),  256, 0, stream>>>(Qh, Ksw, kmean, logits);
    softmax_kernel <<<dim3(8),    256, 0, stream>>>(logits, wgt);
    gateY_kernel   <<<dim3(1024), 256, 0, stream>>>(Yh, wgt, bo, out);
}

// Round 10
// 88.709 us; speedup vs baseline: 3.1544x; 1.0297x over previous
//
#include <hip/hip_runtime.h>

#define BATCH 8
#define CH 256
#define HWSZ 1024
#define BHW 8192

typedef _Float16 f16;
typedef _Float16 f16x4 __attribute__((ext_vector_type(4)));
typedef _Float16 f16x8 __attribute__((ext_vector_type(8)));
typedef float f32x4 __attribute__((ext_vector_type(4)));
typedef unsigned long long u64;
typedef __attribute__((address_space(3))) unsigned int lds_u32;
typedef __attribute__((address_space(1))) const unsigned int glob_u32;

// ---------------- kmeanW: kmean[b][co] = Wk[co,:] . (xsum[b,:]/HW) + bk[co] ----------------
// grid 8 x 256 threads; thread = one (co, b) pair: 256 co x 8 b = 2048 = 8 blocks x 256.
__global__ __launch_bounds__(256) void kmeanW_kernel(
    const float* __restrict__ Wk, const float* __restrict__ bk,
    const float* __restrict__ xsum, float* __restrict__ kmean)
{
    __shared__ float xm[BATCH][CH];
    const int tid = threadIdx.x;
#pragma unroll
    for (int i = 0; i < 8; ++i) xm[i][tid] = xsum[i * 256 + tid] * (1.0f / HWSZ);
    __syncthreads();

    const int co = blockIdx.x * 32 + (tid >> 3);   // [0,256)
    const int b  = tid & 7;
    float acc = 0.f;
    const float4* w = (const float4*)(Wk + (size_t)co * CH);
    for (int c4 = 0; c4 < 64; ++c4) {
        float4 wv = w[c4];
        acc = fmaf(wv.x, xm[b][c4 * 4 + 0], acc);
        acc = fmaf(wv.y, xm[b][c4 * 4 + 1], acc);
        acc = fmaf(wv.z, xm[b][c4 * 4 + 2], acc);
        acc = fmaf(wv.w, xm[b][c4 * 4 + 3], acc);
    }
    kmean[b * 256 + co] = acc + bk[co];
}

// ---------------- pgemmQKY: Q, K, Y from one x-tile; co-SPLIT for 2 blocks/CU ----------------
// grid 512: px-tile p = bid&255 (32 px), co-half h = bid>>8 (128 of 256 rows; same XCD for both
// halves of a px-tile). 256 threads = 4 waves; wave owns 32 co rows (t=2).
// Q/K: split-x K=512 (fp32-class). Y: hi-only (gate attenuates err). xsum atomics from h==0.
__global__ __launch_bounds__(256, 2) void pgemmQKY_kernel(
    const float* __restrict__ x,
    const float* __restrict__ Wq, const float* __restrict__ Wk, const float* __restrict__ Wo,
    const float* __restrict__ bq, const float* __restrict__ bk,
    f16* __restrict__ Qh, char* __restrict__ Ksw, f16* __restrict__ Yh,
    float* __restrict__ xsum)
{
    __shared__ __align__(16) char kbuf[32 * 1024];     // x^T split tile (hi|lo per px), full 256 ch
    __shared__ __align__(16) float xt[256][36];        // fp32 staging; reused as epilogue bounce
    f16* tile = (f16*)&xt[0][0];                       // 128 co x 32 px f16 bounce (8 KB)
    char* tileb = (char*)&xt[0][0];                    // 32 px x 256 B K bounce (8 KB)

    const int bid  = blockIdx.x;
    const int h    = bid >> 8;          // co-half
    const int p    = bid & 255;         // px-tile
    const int pxg0 = p * 32;
    const int b    = pxg0 >> 10;
    const int hw0  = pxg0 & 1023;
    const int tid  = threadIdx.x;
    const int lane = tid & 63;
    const int wid  = tid >> 6;          // 4 waves
    const int m = lane & 15, g = lane >> 4;
    const int coW = h * 128;            // this block's co window base

    // Phase A: coalesced load of x[b][0..255][hw0..+32)
    {
        const int f4 = tid & 7;
        const int cs = tid >> 3;           // [0,32)
#pragma unroll
        for (int pass = 0; pass < 8; ++pass) {
            const int c = pass * 32 + cs;
            float4 v = *(const float4*)(x + ((size_t)b * CH + c) * HWSZ + hw0 + f4 * 4);
            *(float4*)&xt[c][f4 * 4] = v;
        }
    }
    __syncthreads();

    // Phase B: transpose + hi/lo split into kbuf (full 256 channels)
    {
        const int px = tid & 31;
        const int q8 = tid >> 5;           // [0,8)
        const int sw = (px & 7) << 4;
#pragma unroll
        for (int r = 0; r < 4; ++r) {
            f16x8 hi, lo;
#pragma unroll
            for (int i = 0; i < 8; ++i) {
                const int c = q8 * 32 + r * 8 + i;
                float v = xt[c][px];
                f16 hv = (f16)v;
                hi[i] = hv;
                lo[i] = (f16)(v - (float)hv);
            }
            const int base = q8 * 64 + r * 16;
            *(f16x8*)(kbuf + px * 1024 + (base ^ sw)) = hi;
            *(f16x8*)(kbuf + px * 1024 + 512 + (base ^ sw)) = lo;
        }
    }

    // xsum partials (h==0 blocks only; atomic across px-tiles)
    if (h == 0) {
        float s = 0.f;
#pragma unroll
        for (int i4 = 0; i4 < 8; ++i4) {
            float4 v = *(const float4*)&xt[tid][i4 * 4];
            s += v.x + v.y + v.z + v.w;
        }
        atomicAdd(&xsum[b * 256 + tid], s);
    }

    f16x8 a[2][8];
#define LOAD_W(Wsel)                                                                     \
    {                                                                                    \
        _Pragma("unroll")                                                                \
        for (int t = 0; t < 2; ++t)                                                      \
            _Pragma("unroll")                                                            \
            for (int kk = 0; kk < 8; ++kk) {                                             \
                const float* wrow = (Wsel) + (size_t)(coW + wid * 32 + t * 16 + m) * CH + kk * 32 + g * 8; \
                float4 w0 = *(const float4*)(wrow);                                      \
                float4 w1 = *(const float4*)(wrow + 4);                                  \
                f16x8 av;                                                                \
                av[0] = (f16)w0.x; av[1] = (f16)w0.y; av[2] = (f16)w0.z; av[3] = (f16)w0.w; \
                av[4] = (f16)w1.x; av[5] = (f16)w1.y; av[6] = (f16)w1.z; av[7] = (f16)w1.w; \
                a[t][kk] = av;                                                           \
            }                                                                            \
    }
    LOAD_W(Wq);
    __syncthreads();   // kbuf ready; all xt reads (B + xsum) done

    const int sw0 = (m & 7) << 4;
    const f32x4 vz = {0.f, 0.f, 0.f, 0.f};
    f32x4 acc[2][2];

#define MFMA_PASS(NKS)                                                                   \
    {                                                                                    \
        _Pragma("unroll")                                                                \
        for (int t = 0; t < 2; ++t) { acc[t][0] = vz; acc[t][1] = vz; }                  \
        _Pragma("unroll")                                                                \
        for (int ks = 0; ks < (NKS); ++ks) {                                             \
            const int X = ks * 64 + g * 16;                                              \
            f16x8 b0 = *(const f16x8*)(kbuf + m * 1024 + (X ^ sw0));                     \
            f16x8 b1 = *(const f16x8*)(kbuf + (16 + m) * 1024 + (X ^ sw0));              \
            _Pragma("unroll")                                                            \
            for (int t = 0; t < 2; ++t) {                                                \
                acc[t][0] = __builtin_amdgcn_mfma_f32_16x16x32_f16(a[t][ks & 7], b0, acc[t][0], 0, 0, 0); \
                acc[t][1] = __builtin_amdgcn_mfma_f32_16x16x32_f16(a[t][ks & 7], b1, acc[t][1], 0, 0, 0); \
            }                                                                            \
        }                                                                                \
    }

    // ---- Q pass (K=512 split) ----
    MFMA_PASS(16);

    // Q epilogue: bounce to LDS (local co window), coalesced f16x8 stores
#pragma unroll
    for (int t = 0; t < 2; ++t) {
        const int lco0 = wid * 32 + t * 16 + 4 * g;          // local [0,128)
        float4 bv = *(const float4*)(bq + coW + lco0);
        float ba[4] = {bv.x, bv.y, bv.z, bv.w};
#pragma unroll
        for (int u = 0; u < 2; ++u) {
            const int px = u * 16 + m;
#pragma unroll
            for (int j = 0; j < 4; ++j)
                tile[(lco0 + j) * 32 + (px ^ (j << 3))] = (f16)(acc[t][u][j] + ba[j]);
        }
    }
    __syncthreads();
#pragma unroll
    for (int pass = 0; pass < 2; ++pass) {
        const int lco = pass * 64 + (tid >> 2);
        const int run = tid & 3;
        f16x8 v = *(const f16x8*)(tile + lco * 32 + ((run * 8) ^ ((lco & 3) << 3)));
        *(f16x8*)(Qh + ((size_t)b * CH + coW + lco) * HWSZ + hw0 + run * 8) = v;
    }

    // ---- K pass (K=512 split) ----
    LOAD_W(Wk);
    MFMA_PASS(16);
    __syncthreads();   // Q tile reads complete before K bounce overwrites

#pragma unroll
    for (int t = 0; t < 2; ++t) {
        const int lco0 = wid * 32 + t * 16 + 4 * g;
        float4 bv = *(const float4*)(bk + coW + lco0);
        float ba[4] = {bv.x, bv.y, bv.z, bv.w};
#pragma unroll
        for (int u = 0; u < 2; ++u) {
            const int px = u * 16 + m;
            f16x4 pk;
#pragma unroll
            for (int j = 0; j < 4; ++j) pk[j] = (f16)(acc[t][u][j] + ba[j]);
            *(f16x4*)(tileb + px * 256 + ((lco0 * 2) ^ (m << 3))) = pk;
        }
    }
    __syncthreads();
    {
        const int px = tid & 31;
        const int rp = tid >> 5;           // [0,8)
        const int kloc = (px & 15) << 3;
        const int kglb = (px & 7) << 4;
        char* grow = Ksw + (size_t)(pxg0 + px) * 512 + h * 256;
#pragma unroll
        for (int i = 0; i < 2; ++i) {
            const int rl = rp + i * 8;     // [0,16): 16B units within the 256B half-row
            u64 a0 = *(const u64*)(tileb + px * 256 + ((rl * 16) ^ kloc));
            u64 a1 = *(const u64*)(tileb + px * 256 + ((rl * 16 + 8) ^ kloc));
            char* gdst = grow + ((rl * 16) ^ kglb);
            *(u64*)gdst = a0;
            *(u64*)(gdst + 8) = a1;
        }
    }

    // ---- Y pass (hi-only, K=256; pre-gate, no bias) ----
    LOAD_W(Wo);
    MFMA_PASS(8);
    __syncthreads();   // K tileb reads complete before Y bounce overwrites

#pragma unroll
    for (int t = 0; t < 2; ++t) {
        const int lco0 = wid * 32 + t * 16 + 4 * g;
#pragma unroll
        for (int u = 0; u < 2; ++u) {
            const int px = u * 16 + m;
#pragma unroll
            for (int j = 0; j < 4; ++j)
                tile[(lco0 + j) * 32 + (px ^ (j << 3))] = (f16)acc[t][u][j];
        }
    }
    __syncthreads();
#pragma unroll
    for (int pass = 0; pass < 2; ++pass) {
        const int lco = pass * 64 + (tid >> 2);
        const int run = tid & 3;
        f16x8 v = *(const f16x8*)(tile + lco * 32 + ((run * 8) ^ ((lco & 3) << 3)));
        *(f16x8*)(Yh + ((size_t)b * CH + coW + lco) * HWSZ + hw0 + run * 8) = v;
    }
#undef MFMA_PASS
#undef LOAD_W
}

// ---------------- score: 128 rows x 1024 cols/block; exclusive rowdq write (no atomics) ----------------
// grid 512: batch = bid&7 (XCD-affine), rowblock = bid>>3. Counted vmcnt (T4) in K-loop.
// rowdq[r*8+batch] = rowmax(r,batch) + q_r . kmean[batch]   (summed & scaled in softmax)
__global__ __launch_bounds__(256, 2) void score_kernel(
    const f16* __restrict__ Qh, const char* __restrict__ Ksw,
    const float* __restrict__ kmean, float* __restrict__ rowdq)
{
    __shared__ __align__(16) char kbuf[2][32768];   // 64 cols x 512B, double buffered
    __shared__ float lds_rm[128][2];
    __shared__ float lds_dq[128];
    __shared__ float km[CH];

    const int batch = blockIdx.x & 7;
    const int r0    = (blockIdx.x >> 3) * 128;
    const int tid   = threadIdx.x;
    const int lane  = tid & 63;
    const int wid   = tid >> 6;          // 4 waves
    const int wr = wid >> 1, wc = wid & 1;
    const int m = lane & 15, g = lane >> 4;
    const int rbase = r0 + wr * 64;

    km[tid] = kmean[batch * 256 + tid];

    const char* kbase = Ksw + (size_t)batch * HWSZ * 512;

#define STAGE(buf, ch)                                                                   \
    {                                                                                    \
        const char* _src = kbase + (ch) * 64 * 512 + tid * 16;                           \
        char* _dst = &kbuf[buf][tid * 16];                                               \
        _Pragma("unroll")                                                                \
        for (int k = 0; k < 8; ++k)                                                      \
            __builtin_amdgcn_global_load_lds((glob_u32*)(_src + k * 4096),               \
                                             (lds_u32*)(_dst + k * 4096), 16, 0, 0);     \
    }

    STAGE(0, 0);

    // A fragments: 64 rows x K=256 in registers
    f16x8 a[4][8];
#pragma unroll
    for (int t = 0; t < 4; ++t)
#pragma unroll
        for (int kk = 0; kk < 8; ++kk)
            a[t][kk] = *(const f16x8*)(Qh + (size_t)(rbase + t * 16 + m) * CH + kk * 32 + 8 * g);

    int boff[8][2];
    {
        const int sw = (m & 7) << 4;
#pragma unroll
        for (int kk = 0; kk < 8; ++kk)
#pragma unroll
            for (int u2 = 0; u2 < 2; ++u2) {
                const int col = wc * 32 + u2 * 16 + m;
                boff[kk][u2] = col * 512 + ((kk * 64 + g * 16) ^ sw);
            }
    }

    float rm[4][4];
#pragma unroll
    for (int t = 0; t < 4; ++t)
#pragma unroll
        for (int jj = 0; jj < 4; ++jj) rm[t][jj] = -1e30f;

    int cur = 0;
    for (int ch = 0; ch < 16; ++ch) {
        if (ch < 15) {
            STAGE(cur ^ 1, ch + 1);
            asm volatile("s_waitcnt vmcnt(8)" ::: "memory");
        } else {
            asm volatile("s_waitcnt vmcnt(0)" ::: "memory");
        }
        __builtin_amdgcn_s_barrier();

        const char* kb = &kbuf[cur][0];
        f32x4 acc[4][2];
        const f32x4 vz = {0.f, 0.f, 0.f, 0.f};
#pragma unroll
        for (int t = 0; t < 4; ++t) { acc[t][0] = vz; acc[t][1] = vz; }

#pragma unroll
        for (int kk = 0; kk < 8; ++kk) {
            f16x8 bfr[2];
            bfr[0] = *(const f16x8*)(kb + boff[kk][0]);
            bfr[1] = *(const f16x8*)(kb + boff[kk][1]);
#pragma unroll
            for (int t = 0; t < 4; ++t) {
                acc[t][0] = __builtin_amdgcn_mfma_f32_16x16x32_f16(a[t][kk], bfr[0], acc[t][0], 0, 0, 0);
                acc[t][1] = __builtin_amdgcn_mfma_f32_16x16x32_f16(a[t][kk], bfr[1], acc[t][1], 0, 0, 0);
            }
        }

#pragma unroll
        for (int t = 0; t < 4; ++t)
#pragma unroll
            for (int jj = 0; jj < 4; ++jj)
                rm[t][jj] = fmaxf(rm[t][jj], fmaxf(acc[t][0][jj], acc[t][1][jj]));

        asm volatile("" ::: "memory");
        __builtin_amdgcn_s_barrier();
        cur ^= 1;
    }
#undef STAGE

    // reduce max over the 16 column lanes
#pragma unroll
    for (int d = 1; d < 16; d <<= 1)
#pragma unroll
        for (int t = 0; t < 4; ++t)
#pragma unroll
            for (int jj = 0; jj < 4; ++jj)
                rm[t][jj] = fmaxf(rm[t][jj], __shfl_xor(rm[t][jj], d, 64));

    // q . kmean[batch] per lane-row (rbase + t*16 + m), reduced over g
    float dq[4];
#pragma unroll
    for (int t = 0; t < 4; ++t) {
        float s = 0.f;
#pragma unroll
        for (int kk = 0; kk < 8; ++kk)
#pragma unroll
            for (int i = 0; i < 8; ++i)
                s = fmaf((float)a[t][kk][i], km[kk * 32 + 8 * g + i], s);
        s += __shfl_xor(s, 16, 64);
        s += __shfl_xor(s, 32, 64);
        dq[t] = s;
    }

    if (m == 0) {
#pragma unroll
        for (int t = 0; t < 4; ++t)
#pragma unroll
            for (int jj = 0; jj < 4; ++jj)
                lds_rm[wr * 64 + t * 16 + g * 4 + jj][wc] = rm[t][jj];
    }
    if (wc == 0 && lane < 16) {
#pragma unroll
        for (int t = 0; t < 4; ++t)
            lds_dq[wr * 64 + t * 16 + lane] = dq[t];
    }
    __syncthreads();
    if (tid < 128)
        rowdq[(size_t)(r0 + tid) * 8 + batch] =
            fmaxf(lds_rm[tid][0], lds_rm[tid][1]) + lds_dq[tid];
}

// ---------------- softmax: logits from rowdq, then softmax over HW per batch ----------------
__global__ __launch_bounds__(256) void softmax_kernel(const float* __restrict__ rowdq,
                                                      float* __restrict__ wgt)
{
    const int br = blockIdx.x, tid = threadIdx.x;
    __shared__ float red[256];
    float l[4];
#pragma unroll
    for (int i = 0; i < 4; ++i) {
        const size_t r = (size_t)br * HWSZ + i * 256 + tid;
        float4 v0 = *(const float4*)(rowdq + r * 8);
        float4 v1 = *(const float4*)(rowdq + r * 8 + 4);
        l[i] = (v0.x + v0.y + v0.z + v0.w + v1.x + v1.y + v1.z + v1.w) * (1.0f / 128.0f);
    }

    float mx = fmaxf(fmaxf(l[0], l[1]), fmaxf(l[2], l[3]));
    red[tid] = mx;
    __syncthreads();
    for (int s = 128; s > 0; s >>= 1) {
        if (tid < s) red[tid] = fmaxf(red[tid], red[tid + s]);
        __syncthreads();
    }
    mx = red[0];
    __syncthreads();

    float e[4], sm = 0.f;
#pragma unroll
    for (int i = 0; i < 4; ++i) { e[i] = expf(l[i] - mx); sm += e[i]; }
    red[tid] = sm;
    __syncthreads();
    for (int s = 128; s > 0; s >>= 1) {
        if (tid < s) red[tid] += red[tid + s];
        __syncthreads();
    }
    const float inv = 1.0f / red[0];
#pragma unroll
    for (int i = 0; i < 4; ++i)
        wgt[br * HWSZ + i * 256 + tid] = e[i] * inv;
}

// ---------------- gateY: out = wgt * Y + bo  (1024 blocks: 2,097,152 / (256*8)) ----------------
__global__ __launch_bounds__(256) void gateY_kernel(const f16* __restrict__ Yh,
                                                    const float* __restrict__ wgt,
                                                    const float* __restrict__ bo,
                                                    float* __restrict__ out)
{
    const size_t idx = ((size_t)blockIdx.x * 256 + threadIdx.x) * 8;
    const int b  = (int)(idx >> 18);
    const int c  = (int)(idx >> 10) & 255;
    const int hw = (int)idx & 1023;

    f16x8 y = *(const f16x8*)(Yh + idx);
    float4 w0 = *(const float4*)(wgt + b * HWSZ + hw);
    float4 w1 = *(const float4*)(wgt + b * HWSZ + hw + 4);
    const float bov = bo[c];

    float4 o0, o1;
    o0.x = fmaf((float)y[0], w0.x, bov); o0.y = fmaf((float)y[1], w0.y, bov);
    o0.z = fmaf((float)y[2], w0.z, bov); o0.w = fmaf((float)y[3], w0.w, bov);
    o1.x = fmaf((float)y[4], w1.x, bov); o1.y = fmaf((float)y[5], w1.y, bov);
    o1.z = fmaf((float)y[6], w1.z, bov); o1.w = fmaf((float)y[7], w1.w, bov);
    *(float4*)(out + idx)     = o0;
    *(float4*)(out + idx + 4) = o1;
}

extern "C" void kernel_launch(void* const* d_in, const int* in_sizes, int n_in,
                              void* d_out, int out_size, void* d_ws, size_t ws_size,
                              hipStream_t stream)
{
    const float* x  = (const float*)d_in[0];
    const float* Wq = (const float*)d_in[1];
    const float* bq = (const float*)d_in[2];
    const float* Wk = (const float*)d_in[3];
    const float* bk = (const float*)d_in[4];
    const float* Wo = (const float*)d_in[5];
    const float* bo = (const float*)d_in[6];
    float* out = (float*)d_out;

    char* ws = (char*)d_ws;
    f16*   Qh     = (f16*)(ws);                                   // 4 MB
    char*  Ksw    = (char*)(ws + (4 << 20));                      // 4 MB (swizzled f16)
    f16*   Yh     = (f16*)(ws + (8 << 20));                       // 4 MB (pre-gate Y, f16)
    float* xsum   = (float*)(ws + (12 << 20));                    // 8 KB (atomic-accumulated)
    float* rowdq  = (float*)(ws + (12 << 20) + (8 << 10));        // 256 KB (exclusive writes)
    float* kmean  = (float*)(ws + (12 << 20) + (264 << 10));      // 8 KB
    float* wgt    = (float*)(ws + (12 << 20) + (272 << 10));      // 32 KB

    hipMemsetAsync(xsum, 0, 8 << 10, stream);

    pgemmQKY_kernel<<<dim3(512),  256, 0, stream>>>(x, Wq, Wk, Wo, bq, bk, Qh, Ksw, Yh, xsum);
    kmeanW_kernel  <<<dim3(8),    256, 0, stream>>>(Wk, bk, xsum, kmean);
    score_kernel   <<<dim3(512),  256, 0, stream>>>(Qh, Ksw, kmean, rowdq);
    softmax_kernel <<<dim3(8),    256, 0, stream>>>(rowdq, wgt);
    gateY_kernel   <<<dim3(1024), 256, 0, stream>>>(Yh, wgt, bo, out);
}